// Round 1
// baseline (4678.568 us; speedup 1.0000x reference)
//
#include <hip/hip_runtime.h>
#include <hip/hip_bf16.h>

// ---------------- float atomic-max via order-preserving uint key ----------
__device__ __forceinline__ unsigned fmax_key(float f) {
    unsigned b = __float_as_uint(f);
    return (b & 0x80000000u) ? ~b : (b | 0x80000000u);
}
__device__ __forceinline__ float fmax_unkey(unsigned u) {
    return (u & 0x80000000u) ? __uint_as_float(u & 0x7fffffffu)
                             : __uint_as_float(~u);
}
#define NEG_INF_KEY 0x007FFFFFu  // fmax_key(-inf)

// ---------------- init kernels -------------------------------------------
__global__ __launch_bounds__(256) void init_stats(unsigned* m1, float* z1,
                                                  unsigned* m2, float* z2, int N) {
    int i = blockIdx.x * 256 + threadIdx.x;
    if (i >= N * 4) return;
    m1[i] = NEG_INF_KEY;
    z1[i] = 0.0f;
    if (i < N) { m2[i] = NEG_INF_KEY; z2[i] = 0.0f; }
}

__global__ __launch_bounds__(256) void set_bias(float* __restrict__ out,
                                                const float* __restrict__ b,
                                                int total) {
    int i = blockIdx.x * 256 + threadIdx.x;
    if (i >= total) return;
    out[i] = b[i & 127];  // hidden2 = 128
}

// ---------------- tiled fp32 GEMM: H[N,M] = X[N,K] @ W[K,M] ---------------
// 64x64 tile per block, 256 threads, 4x4 register blocking, BK=128.
template <int K, int M>
__global__ __launch_bounds__(256) void gemm_tile(const float* __restrict__ X,
                                                 const float* __restrict__ W,
                                                 float* __restrict__ H, int N) {
    __shared__ float xs[64][128 + 4];  // [r][k]
    __shared__ float ws[128][64 + 4];  // [k][c]
    const int t = threadIdx.x;
    const int row0 = blockIdx.x * 64;
    const int col0 = blockIdx.y * 64;
    const int tr = (t / 16) * 4;
    const int tc = (t % 16) * 4;
    float acc[4][4] = {};
    for (int kt = 0; kt < K; kt += 128) {
        // load X tile (64 x 128) = 2048 float4
        #pragma unroll
        for (int i = 0; i < 8; ++i) {
            int id = t + i * 256;
            int r = id / 32;
            int k4 = (id % 32) * 4;
            float4 v = make_float4(0.f, 0.f, 0.f, 0.f);
            if (row0 + r < N)
                v = *(const float4*)(X + (size_t)(row0 + r) * K + kt + k4);
            xs[r][k4 + 0] = v.x; xs[r][k4 + 1] = v.y;
            xs[r][k4 + 2] = v.z; xs[r][k4 + 3] = v.w;
        }
        // load W tile (128 x 64) = 2048 float4
        #pragma unroll
        for (int i = 0; i < 8; ++i) {
            int id = t + i * 256;
            int k = id / 16;
            int c4 = (id % 16) * 4;
            float4 v = *(const float4*)(W + (size_t)(kt + k) * M + col0 + c4);
            ws[k][c4 + 0] = v.x; ws[k][c4 + 1] = v.y;
            ws[k][c4 + 2] = v.z; ws[k][c4 + 3] = v.w;
        }
        __syncthreads();
        #pragma unroll 4
        for (int k = 0; k < 128; ++k) {
            float xv[4], wv[4];
            #pragma unroll
            for (int j = 0; j < 4; ++j) xv[j] = xs[tr + j][k];
            #pragma unroll
            for (int j = 0; j < 4; ++j) wv[j] = ws[k][tc + j];
            #pragma unroll
            for (int a = 0; a < 4; ++a)
                #pragma unroll
                for (int b = 0; b < 4; ++b) acc[a][b] += xv[a] * wv[b];
        }
        __syncthreads();
    }
    #pragma unroll
    for (int a = 0; a < 4; ++a) {
        int r = row0 + tr + a;
        if (r < N) {
            #pragma unroll
            for (int b = 0; b < 4; ++b)
                H[(size_t)r * M + col0 + tc + b] = acc[a][b];
        }
    }
}

// ---------------- per-node attention dots ---------------------------------
// layer1: H=4 heads, C=64. one wave per (node, head). grid = N, block = 256.
__global__ __launch_bounds__(256) void attn_e4(const float* __restrict__ h,
                                               const float* __restrict__ a_src,
                                               const float* __restrict__ a_dst,
                                               float* __restrict__ es,
                                               float* __restrict__ ed, int N) {
    int hd = threadIdx.x >> 6;
    int lane = threadIdx.x & 63;
    int n = blockIdx.x;
    float v = h[(size_t)n * 256 + hd * 64 + lane];
    float s = v * a_src[hd * 64 + lane];
    float d = v * a_dst[hd * 64 + lane];
    #pragma unroll
    for (int o = 32; o; o >>= 1) { s += __shfl_down(s, o); d += __shfl_down(d, o); }
    if (lane == 0) { es[n * 4 + hd] = s; ed[n * 4 + hd] = d; }
}

// layer2: H=1, C=128. one wave per node, 2 elems/lane. block 256 = 4 nodes.
__global__ __launch_bounds__(256) void attn_e1(const float* __restrict__ h,
                                               const float* __restrict__ a_src,
                                               const float* __restrict__ a_dst,
                                               float* __restrict__ es,
                                               float* __restrict__ ed, int N) {
    int w = threadIdx.x >> 6;
    int lane = threadIdx.x & 63;
    int n = blockIdx.x * 4 + w;
    if (n >= N) return;
    float v0 = h[(size_t)n * 128 + lane], v1 = h[(size_t)n * 128 + 64 + lane];
    float s = v0 * a_src[lane] + v1 * a_src[64 + lane];
    float d = v0 * a_dst[lane] + v1 * a_dst[64 + lane];
    #pragma unroll
    for (int o = 32; o; o >>= 1) { s += __shfl_down(s, o); d += __shfl_down(d, o); }
    if (lane == 0) { es[n] = s; ed[n] = d; }
}

// ---------------- edge passes, layer 1 (4 heads) --------------------------
__global__ __launch_bounds__(256) void edge_max4(const int* __restrict__ src,
                                                 const int* __restrict__ dst,
                                                 int E, int Etot,
                                                 const float* __restrict__ es,
                                                 const float* __restrict__ ed,
                                                 float* __restrict__ ebuf,
                                                 unsigned* __restrict__ m) {
    int idx = blockIdx.x * 256 + threadIdx.x;
    if (idx >= Etot * 4) return;
    int k = idx >> 2, h = idx & 3;
    int s = k < E ? src[k] : k - E;
    int d = k < E ? dst[k] : k - E;
    float e = es[s * 4 + h] + ed[d * 4 + h];
    e = e > 0.f ? e : 0.2f * e;  // leaky_relu, PyG default slope
    ebuf[idx] = e;
    atomicMax(m + d * 4 + h, fmax_key(e));
}

__global__ __launch_bounds__(256) void edge_exp4(const int* __restrict__ src,
                                                 const int* __restrict__ dst,
                                                 int E, int Etot,
                                                 float* __restrict__ ebuf,
                                                 const unsigned* __restrict__ m,
                                                 float* __restrict__ z) {
    int idx = blockIdx.x * 256 + threadIdx.x;
    if (idx >= Etot * 4) return;
    int k = idx >> 2, h = idx & 3;
    int d = k < E ? dst[k] : k - E;
    float p = expf(ebuf[idx] - fmax_unkey(m[d * 4 + h]));
    ebuf[idx] = p;
    atomicAdd(z + d * 4 + h, p);
}

// 4 edges per block; 64 lanes per edge; lane covers 4 channels (float4).
__global__ __launch_bounds__(256) void edge_agg4(const int* __restrict__ src,
                                                 const int* __restrict__ dst,
                                                 int E, int Etot,
                                                 const float* __restrict__ h1,
                                                 const float* __restrict__ p,
                                                 const float* __restrict__ z,
                                                 float* __restrict__ out) {
    int eidx = blockIdx.x * 4 + (threadIdx.x >> 6);
    int lane = threadIdx.x & 63;
    if (eidx >= Etot) return;
    int s = eidx < E ? src[eidx] : eidx - E;
    int d = eidx < E ? dst[eidx] : eidx - E;
    int h = lane >> 4;
    float alpha = p[eidx * 4 + h] / z[d * 4 + h];
    float4 v = ((const float4*)(h1 + (size_t)s * 256))[lane];
    float* o = out + (size_t)d * 256 + lane * 4;
    atomicAdd(o + 0, alpha * v.x);
    atomicAdd(o + 1, alpha * v.y);
    atomicAdd(o + 2, alpha * v.z);
    atomicAdd(o + 3, alpha * v.w);
}

// ---------------- edge passes, layer 2 (1 head, C=128) --------------------
__global__ __launch_bounds__(256) void edge_max1(const int* __restrict__ src,
                                                 const int* __restrict__ dst,
                                                 int E, int Etot,
                                                 const float* __restrict__ es,
                                                 const float* __restrict__ ed,
                                                 float* __restrict__ ebuf,
                                                 unsigned* __restrict__ m) {
    int k = blockIdx.x * 256 + threadIdx.x;
    if (k >= Etot) return;
    int s = k < E ? src[k] : k - E;
    int d = k < E ? dst[k] : k - E;
    float e = es[s] + ed[d];
    e = e > 0.f ? e : 0.2f * e;
    ebuf[k] = e;
    atomicMax(m + d, fmax_key(e));
}

__global__ __launch_bounds__(256) void edge_exp1(const int* __restrict__ src,
                                                 const int* __restrict__ dst,
                                                 int E, int Etot,
                                                 float* __restrict__ ebuf,
                                                 const unsigned* __restrict__ m,
                                                 float* __restrict__ z) {
    int k = blockIdx.x * 256 + threadIdx.x;
    if (k >= Etot) return;
    int d = k < E ? dst[k] : k - E;
    float p = expf(ebuf[k] - fmax_unkey(m[d]));
    ebuf[k] = p;
    atomicAdd(z + d, p);
}

// 8 edges per block; 32 lanes per edge; lane covers 4 channels (float4).
__global__ __launch_bounds__(256) void edge_agg1(const int* __restrict__ src,
                                                 const int* __restrict__ dst,
                                                 int E, int Etot,
                                                 const float* __restrict__ h2,
                                                 const float* __restrict__ p,
                                                 const float* __restrict__ z,
                                                 float* __restrict__ out) {
    int eidx = blockIdx.x * 8 + (threadIdx.x >> 5);
    int lane = threadIdx.x & 31;
    if (eidx >= Etot) return;
    int s = eidx < E ? src[eidx] : eidx - E;
    int d = eidx < E ? dst[eidx] : eidx - E;
    float alpha = p[eidx] / z[d];
    float4 v = ((const float4*)(h2 + (size_t)s * 128))[lane];
    float* o = out + (size_t)d * 128 + lane * 4;
    atomicAdd(o + 0, alpha * v.x);
    atomicAdd(o + 1, alpha * v.y);
    atomicAdd(o + 2, alpha * v.z);
    atomicAdd(o + 3, alpha * v.w);
}

// ---------------- bias + ELU ----------------------------------------------
__global__ __launch_bounds__(256) void bias_elu(float* __restrict__ h,
                                                const float* __restrict__ b,
                                                int total) {
    int i = blockIdx.x * 256 + threadIdx.x;
    if (i >= total) return;
    float v = h[i] + b[i & 255];  // hidden1 = 256
    h[i] = v > 0.f ? v : expm1f(v);
}

// ---------------- launch ---------------------------------------------------
extern "C" void kernel_launch(void* const* d_in, const int* in_sizes, int n_in,
                              void* d_out, int out_size, void* d_ws, size_t ws_size,
                              hipStream_t stream) {
    const float* x   = (const float*)d_in[0];
    const int*   ei  = (const int*)d_in[1];
    const float* W1  = (const float*)d_in[2];
    const float* as1 = (const float*)d_in[3];
    const float* ad1 = (const float*)d_in[4];
    const float* b1  = (const float*)d_in[5];
    const float* W2  = (const float*)d_in[6];
    const float* as2 = (const float*)d_in[7];
    const float* ad2 = (const float*)d_in[8];
    const float* b2  = (const float*)d_in[9];
    float* out = (float*)d_out;

    const int N = in_sizes[0] / 128;   // 50000
    const int E = in_sizes[1] / 2;     // 800000
    const int Etot = E + N;            // self-loops appended
    const int* src = ei;
    const int* dst = ei + E;

    // workspace layout (floats)
    float* A   = (float*)d_ws;                 // h1 [N,256]  then h2 [N,128]
    float* B   = A + (size_t)N * 256;          // out1 [N,256] -> ELU -> layer2 input
    float* C   = B + (size_t)N * 256;          // edge buffer: e/p  [Etot*4]
    float* es1 = C + (size_t)Etot * 4;
    float* ed1 = es1 + (size_t)N * 4;
    unsigned* m1 = (unsigned*)(ed1 + (size_t)N * 4);
    float* z1  = (float*)(m1 + (size_t)N * 4);
    float* es2 = z1 + (size_t)N * 4;
    float* ed2 = es2 + N;
    unsigned* m2 = (unsigned*)(ed2 + N);
    float* z2  = (float*)(m2 + N);

    // ---- init (ws/out are poisoned 0xAA before every timed call) ----
    hipMemsetAsync(B, 0, (size_t)N * 256 * sizeof(float), stream);
    init_stats<<<(N * 4 + 255) / 256, 256, 0, stream>>>(m1, z1, m2, z2, N);
    set_bias<<<(N * 128 + 255) / 256, 256, 0, stream>>>(out, b2, N * 128);

    // ---- layer 1 ----
    dim3 g1((N + 63) / 64, 4);
    gemm_tile<128, 256><<<g1, 256, 0, stream>>>(x, W1, A, N);
    attn_e4<<<N, 256, 0, stream>>>(A, as1, ad1, es1, ed1, N);
    edge_max4<<<(Etot * 4 + 255) / 256, 256, 0, stream>>>(src, dst, E, Etot, es1, ed1, C, m1);
    edge_exp4<<<(Etot * 4 + 255) / 256, 256, 0, stream>>>(src, dst, E, Etot, C, m1, z1);
    edge_agg4<<<(Etot + 3) / 4, 256, 0, stream>>>(src, dst, E, Etot, A, C, z1, B);
    bias_elu<<<(N * 256 + 255) / 256, 256, 0, stream>>>(B, b1, N * 256);

    // ---- layer 2 ----
    dim3 g2((N + 63) / 64, 2);
    gemm_tile<256, 128><<<g2, 256, 0, stream>>>(B, W2, A, N);
    attn_e1<<<(N + 3) / 4, 256, 0, stream>>>(A, as2, ad2, es2, ed2, N);
    edge_max1<<<(Etot + 255) / 256, 256, 0, stream>>>(src, dst, E, Etot, es2, ed2, C, m2);
    edge_exp1<<<(Etot + 255) / 256, 256, 0, stream>>>(src, dst, E, Etot, C, m2, z2);
    edge_agg1<<<(Etot + 7) / 8, 256, 0, stream>>>(src, dst, E, Etot, A, C, z2, out);
}

// Round 2
// 670.085 us; speedup vs baseline: 6.9820x; 6.9820x over previous
//
#include <hip/hip_runtime.h>
#include <hip/hip_bf16.h>
#include <math.h>

// ===================== CSR build =====================

__global__ __launch_bounds__(256) void hist_deg(const int* __restrict__ dst,
                                                int E, int Etot,
                                                int* __restrict__ deg) {
    int k = blockIdx.x * 256 + threadIdx.x;
    if (k >= Etot) return;
    int d = k < E ? dst[k] : k - E;
    atomicAdd(deg + d, 1);
}

// block-local inclusive scan of 256 ints
__global__ __launch_bounds__(256) void scan_local(const int* __restrict__ deg,
                                                  int* __restrict__ partial,
                                                  int* __restrict__ bsum, int N) {
    __shared__ int s[256];
    int t = threadIdx.x;
    int gid = blockIdx.x * 256 + t;
    int v = gid < N ? deg[gid] : 0;
    s[t] = v;
    __syncthreads();
    #pragma unroll
    for (int o = 1; o < 256; o <<= 1) {
        int add = t >= o ? s[t - o] : 0;
        __syncthreads();
        s[t] += add;
        __syncthreads();
    }
    if (gid < N) partial[gid] = s[t];
    if (t == 255) bsum[blockIdx.x] = s[255];
}

__global__ __launch_bounds__(256) void scan_sums(const int* __restrict__ bsum,
                                                 int* __restrict__ boff, int nb) {
    __shared__ int s[256];
    int t = threadIdx.x;
    int v = t < nb ? bsum[t] : 0;
    s[t] = v;
    __syncthreads();
    #pragma unroll
    for (int o = 1; o < 256; o <<= 1) {
        int add = t >= o ? s[t - o] : 0;
        __syncthreads();
        s[t] += add;
        __syncthreads();
    }
    if (t < nb) boff[t] = s[t] - v;  // exclusive
}

__global__ __launch_bounds__(256) void scan_add(const int* __restrict__ partial,
                                                const int* __restrict__ boff,
                                                const int* __restrict__ deg,
                                                int* __restrict__ rowptr,
                                                int* __restrict__ cursor, int N) {
    int gid = blockIdx.x * 256 + threadIdx.x;
    if (gid >= N) return;
    int incl = partial[gid] + boff[blockIdx.x];
    rowptr[gid + 1] = incl;
    cursor[gid] = incl - deg[gid];
    if (gid == 0) rowptr[0] = 0;
}

__global__ __launch_bounds__(256) void scatter_csr(const int* __restrict__ src,
                                                   const int* __restrict__ dst,
                                                   int E, int Etot,
                                                   int* __restrict__ cursor,
                                                   int* __restrict__ col) {
    int k = blockIdx.x * 256 + threadIdx.x;
    if (k >= Etot) return;
    int s = k < E ? src[k] : k - E;
    int d = k < E ? dst[k] : k - E;
    int pos = atomicAdd(cursor + d, 1);
    col[pos] = s;
}

// ===================== GEMM (fp32 VALU) =====================
// H[N,M] = X[N,K] @ W[K,M]; 64x64 tile, 256 thr, 4x4 reg blocking, BK=128.
template <int K, int M>
__global__ __launch_bounds__(256) void gemm_tile(const float* __restrict__ X,
                                                 const float* __restrict__ W,
                                                 float* __restrict__ H, int N) {
    __shared__ float xs[64][128 + 4];
    __shared__ float ws[128][64 + 4];
    const int t = threadIdx.x;
    const int row0 = blockIdx.x * 64;
    const int col0 = blockIdx.y * 64;
    const int tr = (t / 16) * 4;
    const int tc = (t % 16) * 4;
    float acc[4][4] = {};
    for (int kt = 0; kt < K; kt += 128) {
        #pragma unroll
        for (int i = 0; i < 8; ++i) {
            int id = t + i * 256;
            int r = id / 32;
            int k4 = (id % 32) * 4;
            float4 v = make_float4(0.f, 0.f, 0.f, 0.f);
            if (row0 + r < N)
                v = *(const float4*)(X + (size_t)(row0 + r) * K + kt + k4);
            xs[r][k4 + 0] = v.x; xs[r][k4 + 1] = v.y;
            xs[r][k4 + 2] = v.z; xs[r][k4 + 3] = v.w;
        }
        #pragma unroll
        for (int i = 0; i < 8; ++i) {
            int id = t + i * 256;
            int k = id / 16;
            int c4 = (id % 16) * 4;
            float4 v = *(const float4*)(W + (size_t)(kt + k) * M + col0 + c4);
            ws[k][c4 + 0] = v.x; ws[k][c4 + 1] = v.y;
            ws[k][c4 + 2] = v.z; ws[k][c4 + 3] = v.w;
        }
        __syncthreads();
        #pragma unroll 4
        for (int k = 0; k < 128; ++k) {
            float xv[4], wv[4];
            #pragma unroll
            for (int j = 0; j < 4; ++j) xv[j] = xs[tr + j][k];
            #pragma unroll
            for (int j = 0; j < 4; ++j) wv[j] = ws[k][tc + j];
            #pragma unroll
            for (int a = 0; a < 4; ++a)
                #pragma unroll
                for (int b = 0; b < 4; ++b) acc[a][b] += xv[a] * wv[b];
        }
        __syncthreads();
    }
    #pragma unroll
    for (int a = 0; a < 4; ++a) {
        int r = row0 + tr + a;
        if (r < N) {
            #pragma unroll
            for (int b = 0; b < 4; ++b)
                H[(size_t)r * M + col0 + tc + b] = acc[a][b];
        }
    }
}

// ===================== attention dots =====================
__global__ __launch_bounds__(256) void attn_e4(const float* __restrict__ h,
                                               const float* __restrict__ a_src,
                                               const float* __restrict__ a_dst,
                                               float* __restrict__ es,
                                               float* __restrict__ ed, int N) {
    int hd = threadIdx.x >> 6;
    int lane = threadIdx.x & 63;
    int n = blockIdx.x;
    float v = h[(size_t)n * 256 + hd * 64 + lane];
    float s = v * a_src[hd * 64 + lane];
    float d = v * a_dst[hd * 64 + lane];
    #pragma unroll
    for (int o = 32; o; o >>= 1) { s += __shfl_down(s, o); d += __shfl_down(d, o); }
    if (lane == 0) { es[n * 4 + hd] = s; ed[n * 4 + hd] = d; }
}

__global__ __launch_bounds__(256) void attn_e1(const float* __restrict__ h,
                                               const float* __restrict__ a_src,
                                               const float* __restrict__ a_dst,
                                               float* __restrict__ es,
                                               float* __restrict__ ed, int N) {
    int w = threadIdx.x >> 6;
    int lane = threadIdx.x & 63;
    int n = blockIdx.x * 4 + w;
    if (n >= N) return;
    float v0 = h[(size_t)n * 128 + lane], v1 = h[(size_t)n * 128 + 64 + lane];
    float s = v0 * a_src[lane] + v1 * a_src[64 + lane];
    float d = v0 * a_dst[lane] + v1 * a_dst[64 + lane];
    #pragma unroll
    for (int o = 32; o; o >>= 1) { s += __shfl_down(s, o); d += __shfl_down(d, o); }
    if (lane == 0) { es[n] = s; ed[n] = d; }
}

// ===================== fused softmax + aggregate =====================
// Layer 1: 4 heads x 64 channels. One block (256 thr) per dst node; wave = head.
__global__ __launch_bounds__(256) void agg_l1(const int* __restrict__ rowptr,
                                              const int* __restrict__ col,
                                              const float* __restrict__ h1,
                                              const float* __restrict__ es,
                                              const float* __restrict__ ed,
                                              const float* __restrict__ b1,
                                              float* __restrict__ out1, int N) {
    int n = blockIdx.x;
    int h = threadIdx.x >> 6;
    int lane = threadIdx.x & 63;
    int beg = rowptr[n], end = rowptr[n + 1];
    float edv = ed[n * 4 + h];
    // pass 1: max over edges (lane-strided)
    float m = -INFINITY;
    for (int e = beg + lane; e < end; e += 64) {
        float ev = es[col[e] * 4 + h] + edv;
        ev = ev > 0.f ? ev : 0.2f * ev;
        m = fmaxf(m, ev);
    }
    #pragma unroll
    for (int o = 32; o; o >>= 1) m = fmaxf(m, __shfl_xor(m, o));
    // pass 2: denom
    float z = 0.f;
    for (int e = beg + lane; e < end; e += 64) {
        float ev = es[col[e] * 4 + h] + edv;
        ev = ev > 0.f ? ev : 0.2f * ev;
        z += __expf(ev - m);
    }
    #pragma unroll
    for (int o = 32; o; o >>= 1) z += __shfl_xor(z, o);
    float zinv = 1.0f / z;
    // pass 3: aggregate (serial over edges; loads independent, acc chain only)
    float acc = 0.f;
    for (int e = beg; e < end; ++e) {
        int s = col[e];
        float ev = es[s * 4 + h] + edv;
        ev = ev > 0.f ? ev : 0.2f * ev;
        float alpha = __expf(ev - m) * zinv;
        acc = fmaf(alpha, h1[(size_t)s * 256 + h * 64 + lane], acc);
    }
    float v = acc + b1[h * 64 + lane];
    out1[(size_t)n * 256 + h * 64 + lane] = v > 0.f ? v : expm1f(v);  // ELU fused
}

// Layer 2: 1 head x 128 channels. One block (128 thr) per dst node; 2 waves,
// each wave redundantly computes softmax stats, covers 64 channels.
__global__ __launch_bounds__(128) void agg_l2(const int* __restrict__ rowptr,
                                              const int* __restrict__ col,
                                              const float* __restrict__ h2,
                                              const float* __restrict__ es,
                                              const float* __restrict__ ed,
                                              const float* __restrict__ b2,
                                              float* __restrict__ out, int N) {
    int n = blockIdx.x;
    int w = threadIdx.x >> 6;
    int lane = threadIdx.x & 63;
    int beg = rowptr[n], end = rowptr[n + 1];
    float edv = ed[n];
    float m = -INFINITY;
    for (int e = beg + lane; e < end; e += 64) {
        float ev = es[col[e]] + edv;
        ev = ev > 0.f ? ev : 0.2f * ev;
        m = fmaxf(m, ev);
    }
    #pragma unroll
    for (int o = 32; o; o >>= 1) m = fmaxf(m, __shfl_xor(m, o));
    float z = 0.f;
    for (int e = beg + lane; e < end; e += 64) {
        float ev = es[col[e]] + edv;
        ev = ev > 0.f ? ev : 0.2f * ev;
        z += __expf(ev - m);
    }
    #pragma unroll
    for (int o = 32; o; o >>= 1) z += __shfl_xor(z, o);
    float zinv = 1.0f / z;
    float acc = 0.f;
    for (int e = beg; e < end; ++e) {
        int s = col[e];
        float ev = es[s] + edv;
        ev = ev > 0.f ? ev : 0.2f * ev;
        float alpha = __expf(ev - m) * zinv;
        acc = fmaf(alpha, h2[(size_t)s * 128 + w * 64 + lane], acc);
    }
    out[(size_t)n * 128 + w * 64 + lane] = acc + b2[w * 64 + lane];
}

// ===================== launch =====================
extern "C" void kernel_launch(void* const* d_in, const int* in_sizes, int n_in,
                              void* d_out, int out_size, void* d_ws, size_t ws_size,
                              hipStream_t stream) {
    const float* x   = (const float*)d_in[0];
    const int*   ei  = (const int*)d_in[1];
    const float* W1  = (const float*)d_in[2];
    const float* as1 = (const float*)d_in[3];
    const float* ad1 = (const float*)d_in[4];
    const float* b1  = (const float*)d_in[5];
    const float* W2  = (const float*)d_in[6];
    const float* as2 = (const float*)d_in[7];
    const float* ad2 = (const float*)d_in[8];
    const float* b2  = (const float*)d_in[9];
    float* out = (float*)d_out;

    const int N = in_sizes[0] / 128;   // 50000
    const int E = in_sizes[1] / 2;     // 800000
    const int Etot = E + N;
    const int* src = ei;
    const int* dst = ei + E;
    const int NB = (N + 255) / 256;    // 196 scan blocks

    // ---- workspace layout ----
    float* A   = (float*)d_ws;                    // h [N,256]
    float* B   = A + (size_t)N * 256;             // layer1 out / layer2 in [N,256]
    float* es1 = B + (size_t)N * 256;             // [N,4]
    float* ed1 = es1 + (size_t)N * 4;
    float* es2 = ed1 + (size_t)N * 4;             // [N]
    float* ed2 = es2 + N;
    int* deg     = (int*)(ed2 + N);               // [N]
    int* partial = deg + N;                       // [N]
    int* rowptr  = partial + N;                   // [N+1]
    int* cursor  = rowptr + N + 1;                // [N]
    int* col     = cursor + N;                    // [Etot]
    int* bsum    = col + Etot;                    // [256]
    int* boff    = bsum + 256;                    // [256]

    // ---- CSR build (once; shared by both layers) ----
    hipMemsetAsync(deg, 0, (size_t)N * sizeof(int), stream);
    hist_deg<<<(Etot + 255) / 256, 256, 0, stream>>>(dst, E, Etot, deg);
    scan_local<<<NB, 256, 0, stream>>>(deg, partial, bsum, N);
    scan_sums<<<1, 256, 0, stream>>>(bsum, boff, NB);
    scan_add<<<NB, 256, 0, stream>>>(partial, boff, deg, rowptr, cursor, N);
    scatter_csr<<<(Etot + 255) / 256, 256, 0, stream>>>(src, dst, E, Etot, cursor, col);

    // ---- layer 1 ----
    dim3 g1((N + 63) / 64, 4);
    gemm_tile<128, 256><<<g1, 256, 0, stream>>>(x, W1, A, N);
    attn_e4<<<N, 256, 0, stream>>>(A, as1, ad1, es1, ed1, N);
    agg_l1<<<N, 256, 0, stream>>>(rowptr, col, A, es1, ed1, b1, B, N);

    // ---- layer 2 ----
    dim3 g2((N + 63) / 64, 2);
    gemm_tile<256, 128><<<g2, 256, 0, stream>>>(B, W2, A, N);
    attn_e1<<<(N + 3) / 4, 256, 0, stream>>>(A, as2, ad2, es2, ed2, N);
    agg_l2<<<N, 128, 0, stream>>>(rowptr, col, A, es2, ed2, b2, out, N);
}

// Round 3
// 536.223 us; speedup vs baseline: 8.7251x; 1.2496x over previous
//
#include <hip/hip_runtime.h>
#include <hip/hip_bf16.h>
#include <math.h>

// ===================== CSR build =====================

__global__ __launch_bounds__(256) void hist_deg(const int* __restrict__ dst,
                                                int E, int Etot,
                                                int* __restrict__ deg) {
    int k = blockIdx.x * 256 + threadIdx.x;
    if (k >= Etot) return;
    int d = k < E ? dst[k] : k - E;
    atomicAdd(deg + d, 1);
}

__global__ __launch_bounds__(256) void scan_local(const int* __restrict__ deg,
                                                  int* __restrict__ partial,
                                                  int* __restrict__ bsum, int N) {
    __shared__ int s[256];
    int t = threadIdx.x;
    int gid = blockIdx.x * 256 + t;
    int v = gid < N ? deg[gid] : 0;
    s[t] = v;
    __syncthreads();
    #pragma unroll
    for (int o = 1; o < 256; o <<= 1) {
        int add = t >= o ? s[t - o] : 0;
        __syncthreads();
        s[t] += add;
        __syncthreads();
    }
    if (gid < N) partial[gid] = s[t];
    if (t == 255) bsum[blockIdx.x] = s[255];
}

__global__ __launch_bounds__(256) void scan_sums(const int* __restrict__ bsum,
                                                 int* __restrict__ boff, int nb) {
    __shared__ int s[256];
    int t = threadIdx.x;
    int v = t < nb ? bsum[t] : 0;
    s[t] = v;
    __syncthreads();
    #pragma unroll
    for (int o = 1; o < 256; o <<= 1) {
        int add = t >= o ? s[t - o] : 0;
        __syncthreads();
        s[t] += add;
        __syncthreads();
    }
    if (t < nb) boff[t] = s[t] - v;  // exclusive
}

__global__ __launch_bounds__(256) void scan_add(const int* __restrict__ partial,
                                                const int* __restrict__ boff,
                                                const int* __restrict__ deg,
                                                int* __restrict__ rowptr,
                                                int* __restrict__ cursor, int N) {
    int gid = blockIdx.x * 256 + threadIdx.x;
    if (gid >= N) return;
    int incl = partial[gid] + boff[blockIdx.x];
    rowptr[gid + 1] = incl;
    cursor[gid] = incl - deg[gid];
    if (gid == 0) rowptr[0] = 0;
}

__global__ __launch_bounds__(256) void scatter_csr(const int* __restrict__ src,
                                                   const int* __restrict__ dst,
                                                   int E, int Etot,
                                                   int* __restrict__ cursor,
                                                   int* __restrict__ col) {
    int k = blockIdx.x * 256 + threadIdx.x;
    if (k >= Etot) return;
    int s = k < E ? src[k] : k - E;
    int d = k < E ? dst[k] : k - E;
    int pos = atomicAdd(cursor + d, 1);
    col[pos] = s;
}

// ===================== GEMM (fp32 VALU) =====================
template <int K, int M>
__global__ __launch_bounds__(256) void gemm_tile(const float* __restrict__ X,
                                                 const float* __restrict__ W,
                                                 float* __restrict__ H, int N) {
    __shared__ float xs[64][128 + 4];
    __shared__ float ws[128][64 + 4];
    const int t = threadIdx.x;
    const int row0 = blockIdx.x * 64;
    const int col0 = blockIdx.y * 64;
    const int tr = (t / 16) * 4;
    const int tc = (t % 16) * 4;
    float acc[4][4] = {};
    for (int kt = 0; kt < K; kt += 128) {
        #pragma unroll
        for (int i = 0; i < 8; ++i) {
            int id = t + i * 256;
            int r = id / 32;
            int k4 = (id % 32) * 4;
            float4 v = make_float4(0.f, 0.f, 0.f, 0.f);
            if (row0 + r < N)
                v = *(const float4*)(X + (size_t)(row0 + r) * K + kt + k4);
            xs[r][k4 + 0] = v.x; xs[r][k4 + 1] = v.y;
            xs[r][k4 + 2] = v.z; xs[r][k4 + 3] = v.w;
        }
        #pragma unroll
        for (int i = 0; i < 8; ++i) {
            int id = t + i * 256;
            int k = id / 16;
            int c4 = (id % 16) * 4;
            float4 v = *(const float4*)(W + (size_t)(kt + k) * M + col0 + c4);
            ws[k][c4 + 0] = v.x; ws[k][c4 + 1] = v.y;
            ws[k][c4 + 2] = v.z; ws[k][c4 + 3] = v.w;
        }
        __syncthreads();
        #pragma unroll 4
        for (int k = 0; k < 128; ++k) {
            float xv[4], wv[4];
            #pragma unroll
            for (int j = 0; j < 4; ++j) xv[j] = xs[tr + j][k];
            #pragma unroll
            for (int j = 0; j < 4; ++j) wv[j] = ws[k][tc + j];
            #pragma unroll
            for (int a = 0; a < 4; ++a)
                #pragma unroll
                for (int b = 0; b < 4; ++b) acc[a][b] += xv[a] * wv[b];
        }
        __syncthreads();
    }
    #pragma unroll
    for (int a = 0; a < 4; ++a) {
        int r = row0 + tr + a;
        if (r < N) {
            #pragma unroll
            for (int b = 0; b < 4; ++b)
                H[(size_t)r * M + col0 + tc + b] = acc[a][b];
        }
    }
}

// ===================== attention dots =====================
__global__ __launch_bounds__(256) void attn_e4(const float* __restrict__ h,
                                               const float* __restrict__ a_src,
                                               const float* __restrict__ a_dst,
                                               float* __restrict__ es,
                                               float* __restrict__ ed, int N) {
    int hd = threadIdx.x >> 6;
    int lane = threadIdx.x & 63;
    int n = blockIdx.x;
    float v = h[(size_t)n * 256 + hd * 64 + lane];
    float s = v * a_src[hd * 64 + lane];
    float d = v * a_dst[hd * 64 + lane];
    #pragma unroll
    for (int o = 32; o; o >>= 1) { s += __shfl_down(s, o); d += __shfl_down(d, o); }
    if (lane == 0) { es[n * 4 + hd] = s; ed[n * 4 + hd] = d; }
}

__global__ __launch_bounds__(256) void attn_e1(const float* __restrict__ h,
                                               const float* __restrict__ a_src,
                                               const float* __restrict__ a_dst,
                                               float* __restrict__ es,
                                               float* __restrict__ ed, int N) {
    int w = threadIdx.x >> 6;
    int lane = threadIdx.x & 63;
    int n = blockIdx.x * 4 + w;
    if (n >= N) return;
    float v0 = h[(size_t)n * 128 + lane], v1 = h[(size_t)n * 128 + 64 + lane];
    float s = v0 * a_src[lane] + v1 * a_src[64 + lane];
    float d = v0 * a_dst[lane] + v1 * a_dst[64 + lane];
    #pragma unroll
    for (int o = 32; o; o >>= 1) { s += __shfl_down(s, o); d += __shfl_down(d, o); }
    if (lane == 0) { es[n] = s; ed[n] = d; }
}

// ===================== fused softmax + aggregate =====================
// Layer 1: one WAVE per dst node; lane covers channel group lane*4 (float4),
// head = lane>>4. Softmax passes stride edges by 16 within each head group.
__global__ __launch_bounds__(256) void agg_l1(const int* __restrict__ rowptr,
                                              const int* __restrict__ col,
                                              const float* __restrict__ h1,
                                              const float* __restrict__ es,
                                              const float* __restrict__ ed,
                                              const float* __restrict__ b1,
                                              float* __restrict__ out1, int N) {
    int wave = threadIdx.x >> 6;
    int lane = threadIdx.x & 63;
    int n = blockIdx.x * 4 + wave;
    if (n >= N) return;
    int h = lane >> 4;
    int beg = rowptr[n], end = rowptr[n + 1];
    float edv = ed[n * 4 + h];
    // pass 1: per-head max (stride 16 within head group)
    float m = -INFINITY;
    for (int e = beg + (lane & 15); e < end; e += 16) {
        float ev = es[col[e] * 4 + h] + edv;
        ev = ev > 0.f ? ev : 0.2f * ev;
        m = fmaxf(m, ev);
    }
    #pragma unroll
    for (int o = 8; o; o >>= 1) m = fmaxf(m, __shfl_xor(m, o));
    // pass 2: per-head denom
    float z = 0.f;
    for (int e = beg + (lane & 15); e < end; e += 16) {
        float ev = es[col[e] * 4 + h] + edv;
        ev = ev > 0.f ? ev : 0.2f * ev;
        z += __expf(ev - m);
    }
    #pragma unroll
    for (int o = 8; o; o >>= 1) z += __shfl_xor(z, o);
    float zinv = 1.0f / z;
    // pass 3: gather-aggregate, full 1KB row per edge in one float4/lane
    float4 acc = make_float4(0.f, 0.f, 0.f, 0.f);
    #pragma unroll 2
    for (int e = beg; e < end; ++e) {
        int s = col[e];
        float ev = es[s * 4 + h] + edv;
        ev = ev > 0.f ? ev : 0.2f * ev;
        float alpha = __expf(ev - m) * zinv;
        float4 v = *(const float4*)(h1 + (size_t)s * 256 + lane * 4);
        acc.x = fmaf(alpha, v.x, acc.x);
        acc.y = fmaf(alpha, v.y, acc.y);
        acc.z = fmaf(alpha, v.z, acc.z);
        acc.w = fmaf(alpha, v.w, acc.w);
    }
    float4 bv = *(const float4*)(b1 + lane * 4);
    float4 o4;
    o4.x = acc.x + bv.x; o4.x = o4.x > 0.f ? o4.x : expm1f(o4.x);
    o4.y = acc.y + bv.y; o4.y = o4.y > 0.f ? o4.y : expm1f(o4.y);
    o4.z = acc.z + bv.z; o4.z = o4.z > 0.f ? o4.z : expm1f(o4.z);
    o4.w = acc.w + bv.w; o4.w = o4.w > 0.f ? o4.w : expm1f(o4.w);
    *(float4*)(out1 + (size_t)n * 256 + lane * 4) = o4;
}

// Layer 2: one WAVE per dst node, 1 head, C=128. Two edges per iteration:
// lanes 0-31 edge e, lanes 32-63 edge e+1; combine halves via shfl_xor(32).
__global__ __launch_bounds__(256) void agg_l2(const int* __restrict__ rowptr,
                                              const int* __restrict__ col,
                                              const float* __restrict__ h2,
                                              const float* __restrict__ es,
                                              const float* __restrict__ ed,
                                              const float* __restrict__ b2,
                                              float* __restrict__ out, int N) {
    int wave = threadIdx.x >> 6;
    int lane = threadIdx.x & 63;
    int n = blockIdx.x * 4 + wave;
    if (n >= N) return;
    int beg = rowptr[n], end = rowptr[n + 1];
    float edv = ed[n];
    float m = -INFINITY;
    for (int e = beg + lane; e < end; e += 64) {
        float ev = es[col[e]] + edv;
        ev = ev > 0.f ? ev : 0.2f * ev;
        m = fmaxf(m, ev);
    }
    #pragma unroll
    for (int o = 32; o; o >>= 1) m = fmaxf(m, __shfl_xor(m, o));
    float z = 0.f;
    for (int e = beg + lane; e < end; e += 64) {
        float ev = es[col[e]] + edv;
        ev = ev > 0.f ? ev : 0.2f * ev;
        z += __expf(ev - m);
    }
    #pragma unroll
    for (int o = 32; o; o >>= 1) z += __shfl_xor(z, o);
    float zinv = 1.0f / z;
    int half = lane >> 5, l32 = lane & 31;
    float4 acc = make_float4(0.f, 0.f, 0.f, 0.f);
    for (int e = beg; e < end; e += 2) {
        int ee = e + half;
        if (ee < end) {
            int s = col[ee];
            float ev = es[s] + edv;
            ev = ev > 0.f ? ev : 0.2f * ev;
            float alpha = __expf(ev - m) * zinv;
            float4 v = *(const float4*)(h2 + (size_t)s * 128 + l32 * 4);
            acc.x = fmaf(alpha, v.x, acc.x);
            acc.y = fmaf(alpha, v.y, acc.y);
            acc.z = fmaf(alpha, v.z, acc.z);
            acc.w = fmaf(alpha, v.w, acc.w);
        }
    }
    acc.x += __shfl_xor(acc.x, 32);
    acc.y += __shfl_xor(acc.y, 32);
    acc.z += __shfl_xor(acc.z, 32);
    acc.w += __shfl_xor(acc.w, 32);
    if (half == 0) {
        float4 bv = *(const float4*)(b2 + l32 * 4);
        float4 o4 = make_float4(acc.x + bv.x, acc.y + bv.y,
                                acc.z + bv.z, acc.w + bv.w);
        *(float4*)(out + (size_t)n * 128 + l32 * 4) = o4;
    }
}

// ===================== launch =====================
extern "C" void kernel_launch(void* const* d_in, const int* in_sizes, int n_in,
                              void* d_out, int out_size, void* d_ws, size_t ws_size,
                              hipStream_t stream) {
    const float* x   = (const float*)d_in[0];
    const int*   ei  = (const int*)d_in[1];
    const float* W1  = (const float*)d_in[2];
    const float* as1 = (const float*)d_in[3];
    const float* ad1 = (const float*)d_in[4];
    const float* b1  = (const float*)d_in[5];
    const float* W2  = (const float*)d_in[6];
    const float* as2 = (const float*)d_in[7];
    const float* ad2 = (const float*)d_in[8];
    const float* b2  = (const float*)d_in[9];
    float* out = (float*)d_out;

    const int N = in_sizes[0] / 128;   // 50000
    const int E = in_sizes[1] / 2;     // 800000
    const int Etot = E + N;
    const int* src = ei;
    const int* dst = ei + E;
    const int NB = (N + 255) / 256;

    float* A   = (float*)d_ws;                    // h [N,256]
    float* B   = A + (size_t)N * 256;             // layer1 out / layer2 in
    float* es1 = B + (size_t)N * 256;             // [N,4]
    float* ed1 = es1 + (size_t)N * 4;
    float* es2 = ed1 + (size_t)N * 4;             // [N]
    float* ed2 = es2 + N;
    int* deg     = (int*)(ed2 + N);
    int* partial = deg + N;
    int* rowptr  = partial + N;
    int* cursor  = rowptr + N + 1;
    int* col     = cursor + N;
    int* bsum    = col + Etot;
    int* boff    = bsum + 256;

    // ---- CSR build (shared by both layers) ----
    hipMemsetAsync(deg, 0, (size_t)N * sizeof(int), stream);
    hist_deg<<<(Etot + 255) / 256, 256, 0, stream>>>(dst, E, Etot, deg);
    scan_local<<<NB, 256, 0, stream>>>(deg, partial, bsum, N);
    scan_sums<<<1, 256, 0, stream>>>(bsum, boff, NB);
    scan_add<<<NB, 256, 0, stream>>>(partial, boff, deg, rowptr, cursor, N);
    scatter_csr<<<(Etot + 255) / 256, 256, 0, stream>>>(src, dst, E, Etot, cursor, col);

    // ---- layer 1 ----
    dim3 g1((N + 63) / 64, 4);
    gemm_tile<128, 256><<<g1, 256, 0, stream>>>(x, W1, A, N);
    attn_e4<<<N, 256, 0, stream>>>(A, as1, ad1, es1, ed1, N);
    agg_l1<<<(N + 3) / 4, 256, 0, stream>>>(rowptr, col, A, es1, ed1, b1, B, N);

    // ---- layer 2 ----
    dim3 g2((N + 63) / 64, 2);
    gemm_tile<256, 128><<<g2, 256, 0, stream>>>(B, W2, A, N);
    attn_e1<<<(N + 3) / 4, 256, 0, stream>>>(A, as2, ad2, es2, ed2, N);
    agg_l2<<<(N + 3) / 4, 256, 0, stream>>>(rowptr, col, A, es2, ed2, b2, out, N);
}

// Round 4
// 457.051 us; speedup vs baseline: 10.2364x; 1.1732x over previous
//
#include <hip/hip_runtime.h>
#include <hip/hip_bf16.h>
#include <math.h>

// ---- bf16 helpers (bit-level, exact up-convert, RN-even down-convert) ----
__device__ __forceinline__ unsigned short f2bf(float f) {
    unsigned x = __float_as_uint(f);
    unsigned r = x + 0x7FFFu + ((x >> 16) & 1u);
    return (unsigned short)(r >> 16);
}
__device__ __forceinline__ float bf2f(unsigned short u) {
    return __uint_as_float(((unsigned)u) << 16);
}

// ===================== CSR build =====================

__global__ __launch_bounds__(256) void hist_deg(const int* __restrict__ dst,
                                                int E, int Etot,
                                                int* __restrict__ deg) {
    int k = blockIdx.x * 256 + threadIdx.x;
    if (k >= Etot) return;
    int d = k < E ? dst[k] : k - E;
    atomicAdd(deg + d, 1);
}

__global__ __launch_bounds__(256) void scan_local(const int* __restrict__ deg,
                                                  int* __restrict__ partial,
                                                  int* __restrict__ bsum, int N) {
    __shared__ int s[256];
    int t = threadIdx.x;
    int gid = blockIdx.x * 256 + t;
    int v = gid < N ? deg[gid] : 0;
    s[t] = v;
    __syncthreads();
    #pragma unroll
    for (int o = 1; o < 256; o <<= 1) {
        int add = t >= o ? s[t - o] : 0;
        __syncthreads();
        s[t] += add;
        __syncthreads();
    }
    if (gid < N) partial[gid] = s[t];
    if (t == 255) bsum[blockIdx.x] = s[255];
}

__global__ __launch_bounds__(256) void scan_sums(const int* __restrict__ bsum,
                                                 int* __restrict__ boff, int nb) {
    __shared__ int s[256];
    int t = threadIdx.x;
    int v = t < nb ? bsum[t] : 0;
    s[t] = v;
    __syncthreads();
    #pragma unroll
    for (int o = 1; o < 256; o <<= 1) {
        int add = t >= o ? s[t - o] : 0;
        __syncthreads();
        s[t] += add;
        __syncthreads();
    }
    if (t < nb) boff[t] = s[t] - v;  // exclusive
}

__global__ __launch_bounds__(256) void scan_add(const int* __restrict__ partial,
                                                const int* __restrict__ boff,
                                                const int* __restrict__ deg,
                                                int* __restrict__ rowptr,
                                                int* __restrict__ cursor, int N) {
    int gid = blockIdx.x * 256 + threadIdx.x;
    if (gid >= N) return;
    int incl = partial[gid] + boff[blockIdx.x];
    rowptr[gid + 1] = incl;
    cursor[gid] = incl - deg[gid];
    if (gid == 0) rowptr[0] = 0;
}

__global__ __launch_bounds__(256) void scatter_csr(const int* __restrict__ src,
                                                   const int* __restrict__ dst,
                                                   int E, int Etot,
                                                   int* __restrict__ cursor,
                                                   int* __restrict__ col,
                                                   int* __restrict__ dstarr) {
    int k = blockIdx.x * 256 + threadIdx.x;
    if (k >= Etot) return;
    int s = k < E ? src[k] : k - E;
    int d = k < E ? dst[k] : k - E;
    int pos = atomicAdd(cursor + d, 1);
    col[pos] = s;
    dstarr[pos] = d;
}

// ===================== GEMM + fused epilogue =====================
// H16[N,M](bf16) = X[N,K] @ W[K,M]; also computes per-row attention dots
// against a_src/a_dst over this block's 64-col slab.
// DOT4: M=256, slab == head -> direct store es[r*4+head]. else atomicAdd(es+r).
template <int K, int M, bool DOT4>
__global__ __launch_bounds__(256) void gemm_fused(const float* __restrict__ X,
                                                  const float* __restrict__ W,
                                                  unsigned short* __restrict__ H16,
                                                  const float* __restrict__ a_src,
                                                  const float* __restrict__ a_dst,
                                                  float* __restrict__ es,
                                                  float* __restrict__ ed, int N) {
    __shared__ float xs[64][128 + 4];
    __shared__ float ws[128][64 + 4];
    const int t = threadIdx.x;
    const int row0 = blockIdx.x * 64;
    const int col0 = blockIdx.y * 64;
    const int tr = (t / 16) * 4;
    const int tc = (t % 16) * 4;
    float acc[4][4] = {};
    for (int kt = 0; kt < K; kt += 128) {
        #pragma unroll
        for (int i = 0; i < 8; ++i) {
            int id = t + i * 256;
            int r = id / 32;
            int k4 = (id % 32) * 4;
            float4 v = make_float4(0.f, 0.f, 0.f, 0.f);
            if (row0 + r < N)
                v = *(const float4*)(X + (size_t)(row0 + r) * K + kt + k4);
            xs[r][k4 + 0] = v.x; xs[r][k4 + 1] = v.y;
            xs[r][k4 + 2] = v.z; xs[r][k4 + 3] = v.w;
        }
        #pragma unroll
        for (int i = 0; i < 8; ++i) {
            int id = t + i * 256;
            int k = id / 16;
            int c4 = (id % 16) * 4;
            float4 v = *(const float4*)(W + (size_t)(kt + k) * M + col0 + c4);
            ws[k][c4 + 0] = v.x; ws[k][c4 + 1] = v.y;
            ws[k][c4 + 2] = v.z; ws[k][c4 + 3] = v.w;
        }
        __syncthreads();
        #pragma unroll 4
        for (int k = 0; k < 128; ++k) {
            float xv[4], wv[4];
            #pragma unroll
            for (int j = 0; j < 4; ++j) xv[j] = xs[tr + j][k];
            #pragma unroll
            for (int j = 0; j < 4; ++j) wv[j] = ws[k][tc + j];
            #pragma unroll
            for (int a = 0; a < 4; ++a)
                #pragma unroll
                for (int b = 0; b < 4; ++b) acc[a][b] += xv[a] * wv[b];
        }
        __syncthreads();
    }
    // ---- epilogue 1: bf16 store ----
    #pragma unroll
    for (int a = 0; a < 4; ++a) {
        int r = row0 + tr + a;
        if (r < N) {
            ushort4 u;
            u.x = f2bf(acc[a][0]); u.y = f2bf(acc[a][1]);
            u.z = f2bf(acc[a][2]); u.w = f2bf(acc[a][3]);
            *(ushort4*)(H16 + (size_t)r * M + col0 + tc) = u;
        }
    }
    // ---- epilogue 2: attention dots over this 64-col slab ----
    const float* asb = a_src + col0;  // for DOT4, col0 = head*64 and
    const float* adb = a_dst + col0;  // a_src is [4][64] flattened: same addr
    float ps[4] = {}, pd[4] = {};
    #pragma unroll
    for (int a = 0; a < 4; ++a)
        #pragma unroll
        for (int b = 0; b < 4; ++b) {
            ps[a] = fmaf(acc[a][b], asb[tc + b], ps[a]);
            pd[a] = fmaf(acc[a][b], adb[tc + b], pd[a]);
        }
    float* red = &xs[0][0];  // reuse LDS (last __syncthreads already passed)
    int cg = t % 16, rg = t / 16;
    #pragma unroll
    for (int a = 0; a < 4; ++a) {
        red[(rg * 4 + a) * 16 + cg] = ps[a];
        red[1024 + (rg * 4 + a) * 16 + cg] = pd[a];
    }
    __syncthreads();
    if (t < 64) {
        float ss = 0.f, sd = 0.f;
        #pragma unroll
        for (int j = 0; j < 16; ++j) {
            ss += red[t * 16 + j];
            sd += red[1024 + t * 16 + j];
        }
        int r = row0 + t;
        if (r < N) {
            if (DOT4) {
                es[r * 4 + blockIdx.y] = ss;
                ed[r * 4 + blockIdx.y] = sd;
            } else {
                atomicAdd(es + r, ss);
                atomicAdd(ed + r, sd);
            }
        }
    }
}

// ===================== edge-logit pre-gather (CSR order) =====================
// layer1: ebuf[h*Etot + k] = leaky(es1[col[k]][h] + ed1[dstarr[k]][h])
__global__ __launch_bounds__(256) void pre_e4(const int* __restrict__ col,
                                              const int* __restrict__ dstarr,
                                              const float* __restrict__ es,
                                              const float* __restrict__ ed,
                                              float* __restrict__ ebuf, int Etot) {
    int k = blockIdx.x * 256 + threadIdx.x;
    if (k >= Etot) return;
    int s = col[k], d = dstarr[k];
    float4 a = *(const float4*)(es + s * 4);
    float4 b = *(const float4*)(ed + d * 4);
    float v0 = a.x + b.x; v0 = v0 > 0.f ? v0 : 0.2f * v0;
    float v1 = a.y + b.y; v1 = v1 > 0.f ? v1 : 0.2f * v1;
    float v2 = a.z + b.z; v2 = v2 > 0.f ? v2 : 0.2f * v2;
    float v3 = a.w + b.w; v3 = v3 > 0.f ? v3 : 0.2f * v3;
    ebuf[k] = v0;
    ebuf[(size_t)Etot + k] = v1;
    ebuf[(size_t)2 * Etot + k] = v2;
    ebuf[(size_t)3 * Etot + k] = v3;
}

__global__ __launch_bounds__(256) void pre_e1(const int* __restrict__ col,
                                              const int* __restrict__ dstarr,
                                              const float* __restrict__ es,
                                              const float* __restrict__ ed,
                                              float* __restrict__ ebuf, int Etot) {
    int k = blockIdx.x * 256 + threadIdx.x;
    if (k >= Etot) return;
    float v = es[col[k]] + ed[dstarr[k]];
    ebuf[k] = v > 0.f ? v : 0.2f * v;
}

// ===================== fused softmax + aggregate =====================
// Layer 1: one wave per node. head = lane>>4; lane covers 4 bf16 channels.
__global__ __launch_bounds__(256) void agg_l1(const int* __restrict__ rowptr,
                                              const int* __restrict__ col,
                                              const unsigned short* __restrict__ h16,
                                              const float* __restrict__ ebuf,
                                              const float* __restrict__ b1,
                                              float* __restrict__ out1,
                                              int N, int Etot) {
    int wave = threadIdx.x >> 6;
    int lane = threadIdx.x & 63;
    int n = blockIdx.x * 4 + wave;
    if (n >= N) return;
    int h = lane >> 4, l16 = lane & 15;
    int beg = rowptr[n], end = rowptr[n + 1];
    const float* eb = ebuf + (size_t)h * Etot;
    float m = -INFINITY;
    for (int e = beg + l16; e < end; e += 16) m = fmaxf(m, eb[e]);
    #pragma unroll
    for (int o = 8; o; o >>= 1) m = fmaxf(m, __shfl_xor(m, o));
    float z = 0.f;
    for (int e = beg + l16; e < end; e += 16) z += __expf(eb[e] - m);
    #pragma unroll
    for (int o = 8; o; o >>= 1) z += __shfl_xor(z, o);
    float zinv = 1.0f / z;
    float4 acc = make_float4(0.f, 0.f, 0.f, 0.f);
    #pragma unroll 2
    for (int e = beg; e < end; ++e) {
        float alpha = __expf(eb[e] - m) * zinv;
        ushort4 u = *(const ushort4*)(h16 + (size_t)col[e] * 256 + lane * 4);
        acc.x = fmaf(alpha, bf2f(u.x), acc.x);
        acc.y = fmaf(alpha, bf2f(u.y), acc.y);
        acc.z = fmaf(alpha, bf2f(u.z), acc.z);
        acc.w = fmaf(alpha, bf2f(u.w), acc.w);
    }
    float4 bv = *(const float4*)(b1 + lane * 4);
    float4 o4;
    o4.x = acc.x + bv.x; o4.x = o4.x > 0.f ? o4.x : expm1f(o4.x);
    o4.y = acc.y + bv.y; o4.y = o4.y > 0.f ? o4.y : expm1f(o4.y);
    o4.z = acc.z + bv.z; o4.z = o4.z > 0.f ? o4.z : expm1f(o4.z);
    o4.w = acc.w + bv.w; o4.w = o4.w > 0.f ? o4.w : expm1f(o4.w);
    *(float4*)(out1 + (size_t)n * 256 + lane * 4) = o4;
}

// Layer 2: one wave per node, 1 head, C=128. Two edges per iter (half-waves).
__global__ __launch_bounds__(256) void agg_l2(const int* __restrict__ rowptr,
                                              const int* __restrict__ col,
                                              const unsigned short* __restrict__ h16,
                                              const float* __restrict__ ebuf,
                                              const float* __restrict__ b2,
                                              float* __restrict__ out, int N) {
    int wave = threadIdx.x >> 6;
    int lane = threadIdx.x & 63;
    int n = blockIdx.x * 4 + wave;
    if (n >= N) return;
    int beg = rowptr[n], end = rowptr[n + 1];
    float m = -INFINITY;
    for (int e = beg + lane; e < end; e += 64) m = fmaxf(m, ebuf[e]);
    #pragma unroll
    for (int o = 32; o; o >>= 1) m = fmaxf(m, __shfl_xor(m, o));
    float z = 0.f;
    for (int e = beg + lane; e < end; e += 64) z += __expf(ebuf[e] - m);
    #pragma unroll
    for (int o = 32; o; o >>= 1) z += __shfl_xor(z, o);
    float zinv = 1.0f / z;
    int half = lane >> 5, l32 = lane & 31;
    float4 acc = make_float4(0.f, 0.f, 0.f, 0.f);
    for (int e = beg; e < end; e += 2) {
        int ee = e + half;
        if (ee < end) {
            float alpha = __expf(ebuf[ee] - m) * zinv;
            ushort4 u = *(const ushort4*)(h16 + (size_t)col[ee] * 128 + l32 * 4);
            acc.x = fmaf(alpha, bf2f(u.x), acc.x);
            acc.y = fmaf(alpha, bf2f(u.y), acc.y);
            acc.z = fmaf(alpha, bf2f(u.z), acc.z);
            acc.w = fmaf(alpha, bf2f(u.w), acc.w);
        }
    }
    acc.x += __shfl_xor(acc.x, 32);
    acc.y += __shfl_xor(acc.y, 32);
    acc.z += __shfl_xor(acc.z, 32);
    acc.w += __shfl_xor(acc.w, 32);
    if (half == 0) {
        float4 bv = *(const float4*)(b2 + l32 * 4);
        *(float4*)(out + (size_t)n * 128 + l32 * 4) =
            make_float4(acc.x + bv.x, acc.y + bv.y, acc.z + bv.z, acc.w + bv.w);
    }
}

// ===================== launch =====================
extern "C" void kernel_launch(void* const* d_in, const int* in_sizes, int n_in,
                              void* d_out, int out_size, void* d_ws, size_t ws_size,
                              hipStream_t stream) {
    const float* x   = (const float*)d_in[0];
    const int*   ei  = (const int*)d_in[1];
    const float* W1  = (const float*)d_in[2];
    const float* as1 = (const float*)d_in[3];
    const float* ad1 = (const float*)d_in[4];
    const float* b1  = (const float*)d_in[5];
    const float* W2  = (const float*)d_in[6];
    const float* as2 = (const float*)d_in[7];
    const float* ad2 = (const float*)d_in[8];
    const float* b2  = (const float*)d_in[9];
    float* out = (float*)d_out;

    const int N = in_sizes[0] / 128;   // 50000
    const int E = in_sizes[1] / 2;     // 800000
    const int Etot = E + N;
    const int* src = ei;
    const int* dst = ei + E;
    const int NB = (N + 255) / 256;

    // ---- workspace layout (all offsets 16B-aligned) ----
    char* p = (char*)d_ws;
    float* B = (float*)p;                 p += (size_t)N * 256 * 4;  // out1 fp32
    unsigned short* H16 = (unsigned short*)p; p += (size_t)N * 256 * 2;  // bf16 h
    float* ebuf = (float*)p;              p += (size_t)4 * Etot * 4;
    float* es1 = (float*)p;               p += (size_t)N * 4 * 4;
    float* ed1 = (float*)p;               p += (size_t)N * 4 * 4;
    float* es2 = (float*)p;               p += (size_t)N * 4;        // contiguous
    float* ed2 = (float*)p;               p += (size_t)N * 4;        //  with es2
    int* deg = (int*)p;                   p += (size_t)N * 4;
    int* partial = (int*)p;               p += (size_t)N * 4;
    int* cursor = (int*)p;                p += (size_t)N * 4;
    int* col = (int*)p;                   p += (size_t)Etot * 4;
    int* dstarr = (int*)p;                p += (size_t)Etot * 4;
    int* rowptr = (int*)p;                p += (size_t)(N + 1) * 4;
    int* bsum = (int*)p;                  p += 256 * 4;
    int* boff = (int*)p;                  p += 256 * 4;

    // ---- CSR build (shared by both layers) ----
    hipMemsetAsync(deg, 0, (size_t)N * sizeof(int), stream);
    hipMemsetAsync(es2, 0, (size_t)2 * N * sizeof(float), stream);
    hist_deg<<<(Etot + 255) / 256, 256, 0, stream>>>(dst, E, Etot, deg);
    scan_local<<<NB, 256, 0, stream>>>(deg, partial, bsum, N);
    scan_sums<<<1, 256, 0, stream>>>(bsum, boff, NB);
    scan_add<<<NB, 256, 0, stream>>>(partial, boff, deg, rowptr, cursor, N);
    scatter_csr<<<(Etot + 255) / 256, 256, 0, stream>>>(src, dst, E, Etot, cursor,
                                                        col, dstarr);

    // ---- layer 1 ----
    dim3 g1((N + 63) / 64, 4);
    gemm_fused<128, 256, true><<<g1, 256, 0, stream>>>(x, W1, H16, as1, ad1,
                                                       es1, ed1, N);
    pre_e4<<<(Etot + 255) / 256, 256, 0, stream>>>(col, dstarr, es1, ed1, ebuf, Etot);
    agg_l1<<<(N + 3) / 4, 256, 0, stream>>>(rowptr, col, H16, ebuf, b1, B, N, Etot);

    // ---- layer 2 ----
    dim3 g2((N + 63) / 64, 2);
    gemm_fused<256, 128, false><<<g2, 256, 0, stream>>>(B, W2, H16, as2, ad2,
                                                        es2, ed2, N);
    pre_e1<<<(Etot + 255) / 256, 256, 0, stream>>>(col, dstarr, es2, ed2, ebuf, Etot);
    agg_l2<<<(N + 3) / 4, 256, 0, stream>>>(rowptr, col, H16, ebuf, b2, out, N);
}

// Round 5
// 453.503 us; speedup vs baseline: 10.3165x; 1.0078x over previous
//
#include <hip/hip_runtime.h>
#include <hip/hip_bf16.h>
#include <math.h>

typedef short bf16x8 __attribute__((ext_vector_type(8)));
typedef float f32x4 __attribute__((ext_vector_type(4)));

// ---- bf16 helpers (RN-even down-convert, exact up-convert) ----
__device__ __forceinline__ unsigned short f2bf(float f) {
    unsigned x = __float_as_uint(f);
    unsigned r = x + 0x7FFFu + ((x >> 16) & 1u);
    return (unsigned short)(r >> 16);
}
__device__ __forceinline__ float bf2f(unsigned short u) {
    return __uint_as_float(((unsigned)u) << 16);
}

// ===================== CSR build =====================

__global__ __launch_bounds__(256) void hist_deg(const int* __restrict__ dst,
                                                int E, int Etot,
                                                int* __restrict__ deg) {
    int k = blockIdx.x * 256 + threadIdx.x;
    if (k >= Etot) return;
    int d = k < E ? dst[k] : k - E;
    atomicAdd(deg + d, 1);
}

__global__ __launch_bounds__(256) void scan_local(const int* __restrict__ deg,
                                                  int* __restrict__ partial,
                                                  int* __restrict__ bsum, int N) {
    __shared__ int s[256];
    int t = threadIdx.x;
    int gid = blockIdx.x * 256 + t;
    int v = gid < N ? deg[gid] : 0;
    s[t] = v;
    __syncthreads();
    #pragma unroll
    for (int o = 1; o < 256; o <<= 1) {
        int add = t >= o ? s[t - o] : 0;
        __syncthreads();
        s[t] += add;
        __syncthreads();
    }
    if (gid < N) partial[gid] = s[t];
    if (t == 255) bsum[blockIdx.x] = s[255];
}

__global__ __launch_bounds__(256) void scan_sums(const int* __restrict__ bsum,
                                                 int* __restrict__ boff, int nb) {
    __shared__ int s[256];
    int t = threadIdx.x;
    int v = t < nb ? bsum[t] : 0;
    s[t] = v;
    __syncthreads();
    #pragma unroll
    for (int o = 1; o < 256; o <<= 1) {
        int add = t >= o ? s[t - o] : 0;
        __syncthreads();
        s[t] += add;
        __syncthreads();
    }
    if (t < nb) boff[t] = s[t] - v;  // exclusive
}

__global__ __launch_bounds__(256) void scan_add(const int* __restrict__ partial,
                                                const int* __restrict__ boff,
                                                const int* __restrict__ deg,
                                                int* __restrict__ rowptr,
                                                int* __restrict__ cursor, int N) {
    int gid = blockIdx.x * 256 + threadIdx.x;
    if (gid >= N) return;
    int incl = partial[gid] + boff[blockIdx.x];
    rowptr[gid + 1] = incl;
    cursor[gid] = incl - deg[gid];
    if (gid == 0) rowptr[0] = 0;
}

__global__ __launch_bounds__(256) void scatter_csr(const int* __restrict__ src,
                                                   const int* __restrict__ dst,
                                                   int E, int Etot,
                                                   int* __restrict__ cursor,
                                                   int* __restrict__ col,
                                                   int* __restrict__ dstarr) {
    int k = blockIdx.x * 256 + threadIdx.x;
    if (k >= Etot) return;
    int s = k < E ? src[k] : k - E;
    int d = k < E ? dst[k] : k - E;
    int pos = atomicAdd(cursor + d, 1);
    col[pos] = s;
    dstarr[pos] = d;
}

// ===================== conversions =====================
__global__ __launch_bounds__(256) void conv_x(const float* __restrict__ in,
                                              unsigned short* __restrict__ out,
                                              int n4) {
    int i = blockIdx.x * 256 + threadIdx.x;
    if (i >= n4) return;
    float4 v = ((const float4*)in)[i];
    ushort4 u;
    u.x = f2bf(v.x); u.y = f2bf(v.y); u.z = f2bf(v.z); u.w = f2bf(v.w);
    ((ushort4*)out)[i] = u;
}

// W [K][M] fp32 -> Wt [M][K] bf16
template <int K, int M>
__global__ __launch_bounds__(256) void conv_wt(const float* __restrict__ W,
                                               unsigned short* __restrict__ Wt) {
    int id = blockIdx.x * 256 + threadIdx.x;
    if (id >= K * M) return;
    int k = id / M, m = id % M;
    Wt[m * K + k] = f2bf(W[id]);
}

// ===================== Q precompute: Q = W projected on a_src/a_dst ========
// Q1[k][j], j<4: sum_c W1[k][j*64+c]*as1[j][c]; j>=4: with ad1. one wave per k.
__global__ __launch_bounds__(256) void make_q1(const float* __restrict__ W1,
                                               const float* __restrict__ as1,
                                               const float* __restrict__ ad1,
                                               float* __restrict__ Q1) {
    int wave = threadIdx.x >> 6, lane = threadIdx.x & 63;
    int k = blockIdx.x * 4 + wave;
    if (k >= 128) return;
    float p[8];
    #pragma unroll
    for (int h = 0; h < 4; ++h) {
        float w = W1[k * 256 + h * 64 + lane];
        p[h] = w * as1[h * 64 + lane];
        p[4 + h] = w * ad1[h * 64 + lane];
    }
    #pragma unroll
    for (int j = 0; j < 8; ++j)
        #pragma unroll
        for (int o = 32; o; o >>= 1) p[j] += __shfl_xor(p[j], o);
    if (lane < 8) Q1[k * 8 + lane] = p[0];  // placeholder avoided below
    if (lane == 0) {
        #pragma unroll
        for (int j = 0; j < 8; ++j) Q1[k * 8 + j] = p[j];
    }
}

// Q2[k][0] = sum_c W2[k][c]*as2[c]; Q2[k][1] with ad2. one wave per k.
__global__ __launch_bounds__(256) void make_q2(const float* __restrict__ W2,
                                               const float* __restrict__ as2,
                                               const float* __restrict__ ad2,
                                               float* __restrict__ Q2) {
    int wave = threadIdx.x >> 6, lane = threadIdx.x & 63;
    int k = blockIdx.x * 4 + wave;
    if (k >= 256) return;
    float w0 = W2[k * 128 + lane], w1 = W2[k * 128 + 64 + lane];
    float s = w0 * as2[lane] + w1 * as2[64 + lane];
    float d = w0 * ad2[lane] + w1 * ad2[64 + lane];
    #pragma unroll
    for (int o = 32; o; o >>= 1) { s += __shfl_xor(s, o); d += __shfl_xor(d, o); }
    if (lane == 0) { Q2[k * 2] = s; Q2[k * 2 + 1] = d; }
}

// ===================== MFMA GEMM =====================
// H16[N,M](bf16) = Xb[N,K](bf16) @ Wt^T  (Wt is [M][K] bf16 = W^T).
// One wave computes a 16x64 strip: 4 n-tiles of 16x16x32 MFMA over K.
template <int K, int M>
__global__ __launch_bounds__(256) void mfma_gemm(const unsigned short* __restrict__ Xb,
                                                 const unsigned short* __restrict__ Wt,
                                                 unsigned short* __restrict__ H16,
                                                 int N) {
    constexpr int NS = M / 64;
    int wave = threadIdx.x >> 6, lane = threadIdx.x & 63;
    int wid = blockIdx.x * 4 + wave;
    int mt = wid / NS, ns = wid % NS;
    int m0 = mt * 16, n0 = ns * 64;
    if (m0 >= N) return;
    int l15 = lane & 15, quad = lane >> 4;
    f32x4 acc[4] = {};
    const unsigned short* arow = Xb + (size_t)(m0 + l15) * K + quad * 8;
    const unsigned short* brow = Wt + (size_t)(n0 + l15) * K + quad * 8;
    for (int k0 = 0; k0 < K; k0 += 32) {
        bf16x8 a = *(const bf16x8*)(arow + k0);
        #pragma unroll
        for (int nt = 0; nt < 4; ++nt) {
            bf16x8 b = *(const bf16x8*)(brow + (size_t)nt * 16 * K + k0);
            acc[nt] = __builtin_amdgcn_mfma_f32_16x16x32_bf16(a, b, acc[nt], 0, 0, 0);
        }
    }
    // C/D layout: col = lane&15, row = quad*4 + reg  [measured m89/m91]
    #pragma unroll
    for (int nt = 0; nt < 4; ++nt)
        #pragma unroll
        for (int r = 0; r < 4; ++r)
            H16[(size_t)(m0 + quad * 4 + r) * M + n0 + nt * 16 + l15] =
                f2bf(acc[nt][r]);
}

// ===================== attention logits via Q =====================
// es/ed[n] = Xb[n,:] . Q[:, j]  (H heads: j<H -> es, j>=H -> ed). wave/node.
template <int K, int H>
__global__ __launch_bounds__(256) void attn_q(const unsigned short* __restrict__ Xb,
                                              const float* __restrict__ Q,
                                              float* __restrict__ es,
                                              float* __restrict__ ed, int N) {
    constexpr int H2 = 2 * H;
    int wave = threadIdx.x >> 6, lane = threadIdx.x & 63;
    int n = blockIdx.x * 4 + wave;
    if (n >= N) return;
    float p[H2] = {};
    #pragma unroll
    for (int kk = 0; kk < K; kk += 64) {
        float xv = bf2f(Xb[(size_t)n * K + kk + lane]);
        #pragma unroll
        for (int j = 0; j < H2; ++j)
            p[j] = fmaf(xv, Q[(kk + lane) * H2 + j], p[j]);
    }
    #pragma unroll
    for (int j = 0; j < H2; ++j)
        #pragma unroll
        for (int o = 32; o; o >>= 1) p[j] += __shfl_xor(p[j], o);
    if (lane == 0) {
        if (H == 4) {
            #pragma unroll
            for (int h = 0; h < 4; ++h) {
                es[n * 4 + h] = p[h];
                ed[n * 4 + h] = p[4 + h];
            }
        } else {
            es[n] = p[0];
            ed[n] = p[1];
        }
    }
}

// ===================== edge-logit pre-gather (CSR order) ====================
__global__ __launch_bounds__(256) void pre_e4(const int* __restrict__ col,
                                              const int* __restrict__ dstarr,
                                              const float* __restrict__ es,
                                              const float* __restrict__ ed,
                                              float* __restrict__ ebuf, int Etot) {
    int k = blockIdx.x * 256 + threadIdx.x;
    if (k >= Etot) return;
    int s = col[k], d = dstarr[k];
    float4 a = *(const float4*)(es + s * 4);
    float4 b = *(const float4*)(ed + d * 4);
    float v0 = a.x + b.x; v0 = v0 > 0.f ? v0 : 0.2f * v0;
    float v1 = a.y + b.y; v1 = v1 > 0.f ? v1 : 0.2f * v1;
    float v2 = a.z + b.z; v2 = v2 > 0.f ? v2 : 0.2f * v2;
    float v3 = a.w + b.w; v3 = v3 > 0.f ? v3 : 0.2f * v3;
    ebuf[k] = v0;
    ebuf[(size_t)Etot + k] = v1;
    ebuf[(size_t)2 * Etot + k] = v2;
    ebuf[(size_t)3 * Etot + k] = v3;
}

__global__ __launch_bounds__(256) void pre_e1(const int* __restrict__ col,
                                              const int* __restrict__ dstarr,
                                              const float* __restrict__ es,
                                              const float* __restrict__ ed,
                                              float* __restrict__ ebuf, int Etot) {
    int k = blockIdx.x * 256 + threadIdx.x;
    if (k >= Etot) return;
    float v = es[col[k]] + ed[dstarr[k]];
    ebuf[k] = v > 0.f ? v : 0.2f * v;
}

// ===================== fused softmax + aggregate =====================
// Layer 1: one wave per node; head = lane>>4; writes bf16 (feeds GEMM2).
__global__ __launch_bounds__(256) void agg_l1(const int* __restrict__ rowptr,
                                              const int* __restrict__ col,
                                              const unsigned short* __restrict__ h16,
                                              const float* __restrict__ ebuf,
                                              const float* __restrict__ b1,
                                              unsigned short* __restrict__ out16,
                                              int N, int Etot) {
    int wave = threadIdx.x >> 6;
    int lane = threadIdx.x & 63;
    int n = blockIdx.x * 4 + wave;
    if (n >= N) return;
    int h = lane >> 4, l16 = lane & 15;
    int beg = rowptr[n], end = rowptr[n + 1];
    const float* eb = ebuf + (size_t)h * Etot;
    float m = -INFINITY;
    for (int e = beg + l16; e < end; e += 16) m = fmaxf(m, eb[e]);
    #pragma unroll
    for (int o = 8; o; o >>= 1) m = fmaxf(m, __shfl_xor(m, o));
    float z = 0.f;
    for (int e = beg + l16; e < end; e += 16) z += __expf(eb[e] - m);
    #pragma unroll
    for (int o = 8; o; o >>= 1) z += __shfl_xor(z, o);
    float zinv = 1.0f / z;
    float4 acc = make_float4(0.f, 0.f, 0.f, 0.f);
    #pragma unroll 2
    for (int e = beg; e < end; ++e) {
        float alpha = __expf(eb[e] - m) * zinv;
        ushort4 u = *(const ushort4*)(h16 + (size_t)col[e] * 256 + lane * 4);
        acc.x = fmaf(alpha, bf2f(u.x), acc.x);
        acc.y = fmaf(alpha, bf2f(u.y), acc.y);
        acc.z = fmaf(alpha, bf2f(u.z), acc.z);
        acc.w = fmaf(alpha, bf2f(u.w), acc.w);
    }
    float4 bv = *(const float4*)(b1 + lane * 4);
    float4 o4;
    o4.x = acc.x + bv.x; o4.x = o4.x > 0.f ? o4.x : expm1f(o4.x);
    o4.y = acc.y + bv.y; o4.y = o4.y > 0.f ? o4.y : expm1f(o4.y);
    o4.z = acc.z + bv.z; o4.z = o4.z > 0.f ? o4.z : expm1f(o4.z);
    o4.w = acc.w + bv.w; o4.w = o4.w > 0.f ? o4.w : expm1f(o4.w);
    ushort4 u;
    u.x = f2bf(o4.x); u.y = f2bf(o4.y); u.z = f2bf(o4.z); u.w = f2bf(o4.w);
    *(ushort4*)(out16 + (size_t)n * 256 + lane * 4) = u;
}

// Layer 2: one wave per node, C=128, two edges per iter (half-waves).
__global__ __launch_bounds__(256) void agg_l2(const int* __restrict__ rowptr,
                                              const int* __restrict__ col,
                                              const unsigned short* __restrict__ h16,
                                              const float* __restrict__ ebuf,
                                              const float* __restrict__ b2,
                                              float* __restrict__ out, int N) {
    int wave = threadIdx.x >> 6;
    int lane = threadIdx.x & 63;
    int n = blockIdx.x * 4 + wave;
    if (n >= N) return;
    int beg = rowptr[n], end = rowptr[n + 1];
    float m = -INFINITY;
    for (int e = beg + lane; e < end; e += 64) m = fmaxf(m, ebuf[e]);
    #pragma unroll
    for (int o = 32; o; o >>= 1) m = fmaxf(m, __shfl_xor(m, o));
    float z = 0.f;
    for (int e = beg + lane; e < end; e += 64) z += __expf(ebuf[e] - m);
    #pragma unroll
    for (int o = 32; o; o >>= 1) z += __shfl_xor(z, o);
    float zinv = 1.0f / z;
    int half = lane >> 5, l32 = lane & 31;
    float4 acc = make_float4(0.f, 0.f, 0.f, 0.f);
    for (int e = beg; e < end; e += 2) {
        int ee = e + half;
        if (ee < end) {
            float alpha = __expf(ebuf[ee] - m) * zinv;
            ushort4 u = *(const ushort4*)(h16 + (size_t)col[ee] * 128 + l32 * 4);
            acc.x = fmaf(alpha, bf2f(u.x), acc.x);
            acc.y = fmaf(alpha, bf2f(u.y), acc.y);
            acc.z = fmaf(alpha, bf2f(u.z), acc.z);
            acc.w = fmaf(alpha, bf2f(u.w), acc.w);
        }
    }
    acc.x += __shfl_xor(acc.x, 32);
    acc.y += __shfl_xor(acc.y, 32);
    acc.z += __shfl_xor(acc.z, 32);
    acc.w += __shfl_xor(acc.w, 32);
    if (half == 0) {
        float4 bv = *(const float4*)(b2 + l32 * 4);
        *(float4*)(out + (size_t)n * 128 + l32 * 4) =
            make_float4(acc.x + bv.x, acc.y + bv.y, acc.z + bv.z, acc.w + bv.w);
    }
}

// ===================== launch =====================
extern "C" void kernel_launch(void* const* d_in, const int* in_sizes, int n_in,
                              void* d_out, int out_size, void* d_ws, size_t ws_size,
                              hipStream_t stream) {
    const float* x   = (const float*)d_in[0];
    const int*   ei  = (const int*)d_in[1];
    const float* W1  = (const float*)d_in[2];
    const float* as1 = (const float*)d_in[3];
    const float* ad1 = (const float*)d_in[4];
    const float* b1  = (const float*)d_in[5];
    const float* W2  = (const float*)d_in[6];
    const float* as2 = (const float*)d_in[7];
    const float* ad2 = (const float*)d_in[8];
    const float* b2  = (const float*)d_in[9];
    float* out = (float*)d_out;

    const int N = in_sizes[0] / 128;   // 50000
    const int E = in_sizes[1] / 2;     // 800000
    const int Etot = E + N;
    const int* src = ei;
    const int* dst = ei + E;
    const int NB = (N + 255) / 256;

    // ---- workspace layout (16B-aligned chunks) ----
    char* p = (char*)d_ws;
    unsigned short* X16 = (unsigned short*)p; p += (size_t)N * 128 * 2;  // bf16 x
    unsigned short* H16 = (unsigned short*)p; p += (size_t)N * 256 * 2;  // h (both layers)
    unsigned short* B16 = (unsigned short*)p; p += (size_t)N * 256 * 2;  // out1 bf16
    unsigned short* Wt1 = (unsigned short*)p; p += (size_t)256 * 128 * 2;
    unsigned short* Wt2 = (unsigned short*)p; p += (size_t)128 * 256 * 2;
    float* Q1  = (float*)p;               p += 128 * 8 * 4;
    float* Q2  = (float*)p;               p += 256 * 2 * 4;
    float* ebuf = (float*)p;              p += (size_t)4 * Etot * 4;
    float* es1 = (float*)p;               p += (size_t)N * 4 * 4;
    float* ed1 = (float*)p;               p += (size_t)N * 4 * 4;
    float* es2 = (float*)p;               p += (size_t)N * 4;
    float* ed2 = (float*)p;               p += (size_t)N * 4;
    int* deg = (int*)p;                   p += (size_t)N * 4;
    int* partial = (int*)p;               p += (size_t)N * 4;
    int* cursor = (int*)p;                p += (size_t)N * 4;
    int* col = (int*)p;                   p += (size_t)Etot * 4;
    int* dstarr = (int*)p;                p += (size_t)Etot * 4;
    int* rowptr = (int*)p;                p += (size_t)(N + 1) * 4;
    int* bsum = (int*)p;                  p += 256 * 4;
    int* boff = (int*)p;                  p += 256 * 4;

    // ---- CSR build ----
    hipMemsetAsync(deg, 0, (size_t)N * sizeof(int), stream);
    hist_deg<<<(Etot + 255) / 256, 256, 0, stream>>>(dst, E, Etot, deg);
    scan_local<<<NB, 256, 0, stream>>>(deg, partial, bsum, N);
    scan_sums<<<1, 256, 0, stream>>>(bsum, boff, NB);
    scan_add<<<NB, 256, 0, stream>>>(partial, boff, deg, rowptr, cursor, N);
    scatter_csr<<<(Etot + 255) / 256, 256, 0, stream>>>(src, dst, E, Etot, cursor,
                                                        col, dstarr);

    // ---- conversions + Q ----
    conv_x<<<(N * 128 / 4 + 255) / 256, 256, 0, stream>>>(x, X16, N * 128 / 4);
    conv_wt<128, 256><<<(128 * 256 + 255) / 256, 256, 0, stream>>>(W1, Wt1);
    conv_wt<256, 128><<<(256 * 128 + 255) / 256, 256, 0, stream>>>(W2, Wt2);
    make_q1<<<32, 256, 0, stream>>>(W1, as1, ad1, Q1);
    make_q2<<<64, 256, 0, stream>>>(W2, as2, ad2, Q2);

    // ---- layer 1 ----
    mfma_gemm<128, 256><<<(N / 16) * 4 / 4, 256, 0, stream>>>(X16, Wt1, H16, N);
    attn_q<128, 4><<<(N + 3) / 4, 256, 0, stream>>>(X16, Q1, es1, ed1, N);
    pre_e4<<<(Etot + 255) / 256, 256, 0, stream>>>(col, dstarr, es1, ed1, ebuf, Etot);
    agg_l1<<<(N + 3) / 4, 256, 0, stream>>>(rowptr, col, H16, ebuf, b1, B16, N, Etot);

    // ---- layer 2 ----
    mfma_gemm<256, 128><<<((N / 16) * 2 + 3) / 4, 256, 0, stream>>>(B16, Wt2, H16, N);
    attn_q<256, 1><<<(N + 3) / 4, 256, 0, stream>>>(B16, Q2, es2, ed2, N);
    pre_e1<<<(Etot + 255) / 256, 256, 0, stream>>>(col, dstarr, es2, ed2, ebuf, Etot);
    agg_l2<<<(N + 3) / 4, 256, 0, stream>>>(rowptr, col, H16, ebuf, b2, out, N);
}

// Round 6
// 387.606 us; speedup vs baseline: 12.0704x; 1.1700x over previous
//
#include <hip/hip_runtime.h>
#include <hip/hip_bf16.h>
#include <math.h>

typedef short bf16x8 __attribute__((ext_vector_type(8)));
typedef float f32x4 __attribute__((ext_vector_type(4)));

#define DEG_CAP 128  // per-node LDS logit cache; fallback path beyond

// ---- bf16 helpers (RN-even down-convert, exact up-convert) ----
__device__ __forceinline__ unsigned short f2bf(float f) {
    unsigned x = __float_as_uint(f);
    unsigned r = x + 0x7FFFu + ((x >> 16) & 1u);
    return (unsigned short)(r >> 16);
}
__device__ __forceinline__ float bf2f(unsigned short u) {
    return __uint_as_float(((unsigned)u) << 16);
}

// ===================== prep: conv_x + hist + Wt + Q (fused) =====================
__global__ __launch_bounds__(256) void prep(const float* __restrict__ x,
                                            unsigned short* __restrict__ X16, int nx4,
                                            const int* __restrict__ dst, int E, int Etot,
                                            int* __restrict__ deg,
                                            const float* __restrict__ W1,
                                            unsigned short* __restrict__ Wt1,
                                            const float* __restrict__ W2,
                                            unsigned short* __restrict__ Wt2,
                                            const float* __restrict__ as1,
                                            const float* __restrict__ ad1,
                                            float* __restrict__ Q1,
                                            const float* __restrict__ as2,
                                            const float* __restrict__ ad2,
                                            float* __restrict__ Q2,
                                            int nb_convx, int nb_hist) {
    int b = blockIdx.x, t = threadIdx.x;
    if (b < nb_convx) {                       // ---- x fp32 -> bf16 (float4) ----
        int i = b * 256 + t;
        if (i < nx4) {
            float4 v = ((const float4*)x)[i];
            ushort4 u;
            u.x = f2bf(v.x); u.y = f2bf(v.y); u.z = f2bf(v.z); u.w = f2bf(v.w);
            ((ushort4*)X16)[i] = u;
        }
        return;
    }
    b -= nb_convx;
    if (b < nb_hist) {                        // ---- degree histogram ----
        int k = b * 256 + t;
        if (k < Etot) {
            int d = k < E ? dst[k] : k - E;
            atomicAdd(deg + d, 1);
        }
        return;
    }
    b -= nb_hist;
    if (b < 128) {                            // ---- W1 [128][256] -> Wt1 [256][128] bf16
        int id = b * 256 + t;                 // id < 32768
        int k = id >> 8, m = id & 255;
        Wt1[m * 128 + k] = f2bf(W1[id]);
        return;
    }
    b -= 128;
    if (b < 128) {                            // ---- W2 [256][128] -> Wt2 [128][256] bf16
        int id = b * 256 + t;
        int k = id >> 7, m = id & 127;
        Wt2[m * 256 + k] = f2bf(W2[id]);
        return;
    }
    b -= 128;
    int wave = t >> 6, lane = t & 63;
    if (b < 32) {                             // ---- Q1 [128][8] ----
        int k = b * 4 + wave;
        if (k < 128) {
            float p[8];
            #pragma unroll
            for (int h = 0; h < 4; ++h) {
                float w = W1[k * 256 + h * 64 + lane];
                p[h] = w * as1[h * 64 + lane];
                p[4 + h] = w * ad1[h * 64 + lane];
            }
            #pragma unroll
            for (int j = 0; j < 8; ++j)
                #pragma unroll
                for (int o = 32; o; o >>= 1) p[j] += __shfl_xor(p[j], o);
            if (lane == 0) {
                #pragma unroll
                for (int j = 0; j < 8; ++j) Q1[k * 8 + j] = p[j];
            }
        }
        return;
    }
    b -= 32;
    {                                         // ---- Q2 [256][2] ----
        int k = b * 4 + wave;
        if (k < 256) {
            float w0 = W2[k * 128 + lane], w1 = W2[k * 128 + 64 + lane];
            float s = w0 * as2[lane] + w1 * as2[64 + lane];
            float d = w0 * ad2[lane] + w1 * ad2[64 + lane];
            #pragma unroll
            for (int o = 32; o; o >>= 1) { s += __shfl_xor(s, o); d += __shfl_xor(d, o); }
            if (lane == 0) { Q2[k * 2] = s; Q2[k * 2 + 1] = d; }
        }
    }
}

// ===================== CSR scan + scatter =====================
__global__ __launch_bounds__(256) void scan_local(const int* __restrict__ deg,
                                                  int* __restrict__ partial,
                                                  int* __restrict__ bsum, int N) {
    __shared__ int s[256];
    int t = threadIdx.x;
    int gid = blockIdx.x * 256 + t;
    int v = gid < N ? deg[gid] : 0;
    s[t] = v;
    __syncthreads();
    #pragma unroll
    for (int o = 1; o < 256; o <<= 1) {
        int add = t >= o ? s[t - o] : 0;
        __syncthreads();
        s[t] += add;
        __syncthreads();
    }
    if (gid < N) partial[gid] = s[t];
    if (t == 255) bsum[blockIdx.x] = s[255];
}

__global__ __launch_bounds__(256) void scan_sums(const int* __restrict__ bsum,
                                                 int* __restrict__ boff, int nb) {
    __shared__ int s[256];
    int t = threadIdx.x;
    int v = t < nb ? bsum[t] : 0;
    s[t] = v;
    __syncthreads();
    #pragma unroll
    for (int o = 1; o < 256; o <<= 1) {
        int add = t >= o ? s[t - o] : 0;
        __syncthreads();
        s[t] += add;
        __syncthreads();
    }
    if (t < nb) boff[t] = s[t] - v;  // exclusive
}

__global__ __launch_bounds__(256) void scan_add(const int* __restrict__ partial,
                                                const int* __restrict__ boff,
                                                const int* __restrict__ deg,
                                                int* __restrict__ rowptr,
                                                int* __restrict__ cursor, int N) {
    int gid = blockIdx.x * 256 + threadIdx.x;
    if (gid >= N) return;
    int incl = partial[gid] + boff[blockIdx.x];
    rowptr[gid + 1] = incl;
    cursor[gid] = incl - deg[gid];
    if (gid == 0) rowptr[0] = 0;
}

__global__ __launch_bounds__(256) void scatter_csr(const int* __restrict__ src,
                                                   const int* __restrict__ dst,
                                                   int E, int Etot,
                                                   int* __restrict__ cursor,
                                                   int* __restrict__ col) {
    int k = blockIdx.x * 256 + threadIdx.x;
    if (k >= Etot) return;
    int s = k < E ? src[k] : k - E;
    int d = k < E ? dst[k] : k - E;
    int pos = atomicAdd(cursor + d, 1);
    col[pos] = s;
}

// ===================== fused MFMA GEMM + attention logits =====================
// blocks [0,GB): H16 = Xb @ Wt^T (bf16 MFMA, wave = 16x64 strip)
// blocks [GB,..): es/ed = Xb . Q  (wave per node)
template <int K, int M, int H>
__global__ __launch_bounds__(256) void gemm_attn(const unsigned short* __restrict__ Xb,
                                                 const unsigned short* __restrict__ Wt,
                                                 const float* __restrict__ Q,
                                                 unsigned short* __restrict__ H16,
                                                 float* __restrict__ es,
                                                 float* __restrict__ ed,
                                                 int N, int GB) {
    int wave = threadIdx.x >> 6, lane = threadIdx.x & 63;
    if ((int)blockIdx.x < GB) {
        constexpr int NS = M / 64;
        int wid = blockIdx.x * 4 + wave;
        int mt = wid / NS, ns = wid % NS;
        int m0 = mt * 16, n0 = ns * 64;
        if (m0 >= N) return;
        int l15 = lane & 15, quad = lane >> 4;
        int ar = m0 + l15; if (ar >= N) ar = N - 1;   // clamp (dup compute ok)
        f32x4 acc[4] = {};
        const unsigned short* arow = Xb + (size_t)ar * K + quad * 8;
        const unsigned short* brow = Wt + (size_t)(n0 + l15) * K + quad * 8;
        for (int k0 = 0; k0 < K; k0 += 32) {
            bf16x8 a = *(const bf16x8*)(arow + k0);
            #pragma unroll
            for (int nt = 0; nt < 4; ++nt) {
                bf16x8 b = *(const bf16x8*)(brow + (size_t)nt * 16 * K + k0);
                acc[nt] = __builtin_amdgcn_mfma_f32_16x16x32_bf16(a, b, acc[nt], 0, 0, 0);
            }
        }
        // C/D layout: col = lane&15, row = quad*4 + reg
        #pragma unroll
        for (int nt = 0; nt < 4; ++nt)
            #pragma unroll
            for (int r = 0; r < 4; ++r) {
                int row = m0 + quad * 4 + r;
                if (row < N)
                    H16[(size_t)row * M + n0 + nt * 16 + l15] = f2bf(acc[nt][r]);
            }
    } else {
        constexpr int H2 = 2 * H;
        int n = (blockIdx.x - GB) * 4 + wave;
        if (n >= N) return;
        float p[H2] = {};
        #pragma unroll
        for (int kk = 0; kk < K; kk += 64) {
            float xv = bf2f(Xb[(size_t)n * K + kk + lane]);
            #pragma unroll
            for (int j = 0; j < H2; ++j)
                p[j] = fmaf(xv, Q[(kk + lane) * H2 + j], p[j]);
        }
        #pragma unroll
        for (int j = 0; j < H2; ++j)
            #pragma unroll
            for (int o = 32; o; o >>= 1) p[j] += __shfl_xor(p[j], o);
        if (lane == 0) {
            if (H == 4) {
                #pragma unroll
                for (int h = 0; h < 4; ++h) {
                    es[n * 4 + h] = p[h];
                    ed[n * 4 + h] = p[4 + h];
                }
            } else {
                es[n] = p[0];
                ed[n] = p[1];
            }
        }
    }
}

// ===================== fused softmax + aggregate (LDS logit cache) ==========
// Layer 1: one wave per node. head = lane>>4. LDS caches exp(e-m) + col.
__global__ __launch_bounds__(256) void agg_l1(const int* __restrict__ rowptr,
                                              const int* __restrict__ col,
                                              const unsigned short* __restrict__ h16,
                                              const float* __restrict__ es,
                                              const float* __restrict__ ed,
                                              const float* __restrict__ b1,
                                              unsigned short* __restrict__ out16,
                                              int N) {
    __shared__ float pl[4][DEG_CAP * 4];
    __shared__ int ic[4][DEG_CAP];
    int wave = threadIdx.x >> 6, lane = threadIdx.x & 63;
    int n = blockIdx.x * 4 + wave;
    if (n >= N) return;
    int h = lane >> 4, l16 = lane & 15;
    int beg = rowptr[n], end = rowptr[n + 1], deg = end - beg;
    float edv = ed[n * 4 + h];
    float* myp = pl[wave];
    int* myc = ic[wave];
    float m = -INFINITY, z = 0.f, zinv;
    float4 acc = make_float4(0.f, 0.f, 0.f, 0.f);
    if (deg <= DEG_CAP) {
        // pass 1: gather logits, cache, track max (lane-strided per head group)
        for (int i = l16; i < deg; i += 16) {
            int s = col[beg + i];
            if (h == 0) myc[i] = s;
            float e = es[s * 4 + h] + edv;
            e = e > 0.f ? e : 0.2f * e;
            myp[i * 4 + h] = e;
            m = fmaxf(m, e);
        }
        #pragma unroll
        for (int o = 8; o; o >>= 1) m = fmaxf(m, __shfl_xor(m, o));
        // pass 2: exp (same-lane RAW on LDS), cache p, sum
        for (int i = l16; i < deg; i += 16) {
            float p = __expf(myp[i * 4 + h] - m);
            myp[i * 4 + h] = p;
            z += p;
        }
        #pragma unroll
        for (int o = 8; o; o >>= 1) z += __shfl_xor(z, o);
        zinv = 1.0f / z;
        __threadfence_block();  // publish LDS p/col across lanes of this wave
        // pass 3: aggregate; alpha broadcast from LDS, zero exp here
        #pragma unroll 2
        for (int i = 0; i < deg; ++i) {
            float alpha = myp[i * 4 + h] * zinv;
            int s = myc[i];
            ushort4 u = *(const ushort4*)(h16 + (size_t)s * 256 + lane * 4);
            acc.x = fmaf(alpha, bf2f(u.x), acc.x);
            acc.y = fmaf(alpha, bf2f(u.y), acc.y);
            acc.z = fmaf(alpha, bf2f(u.z), acc.z);
            acc.w = fmaf(alpha, bf2f(u.w), acc.w);
        }
    } else {
        // fallback: recompute logits by gather (deg > DEG_CAP, ~never)
        for (int e = beg + l16; e < end; e += 16) {
            float ev = es[col[e] * 4 + h] + edv;
            ev = ev > 0.f ? ev : 0.2f * ev;
            m = fmaxf(m, ev);
        }
        #pragma unroll
        for (int o = 8; o; o >>= 1) m = fmaxf(m, __shfl_xor(m, o));
        for (int e = beg + l16; e < end; e += 16) {
            float ev = es[col[e] * 4 + h] + edv;
            ev = ev > 0.f ? ev : 0.2f * ev;
            z += __expf(ev - m);
        }
        #pragma unroll
        for (int o = 8; o; o >>= 1) z += __shfl_xor(z, o);
        zinv = 1.0f / z;
        for (int e = beg; e < end; ++e) {
            int s = col[e];
            float ev = es[s * 4 + h] + edv;
            ev = ev > 0.f ? ev : 0.2f * ev;
            float alpha = __expf(ev - m) * zinv;
            ushort4 u = *(const ushort4*)(h16 + (size_t)s * 256 + lane * 4);
            acc.x = fmaf(alpha, bf2f(u.x), acc.x);
            acc.y = fmaf(alpha, bf2f(u.y), acc.y);
            acc.z = fmaf(alpha, bf2f(u.z), acc.z);
            acc.w = fmaf(alpha, bf2f(u.w), acc.w);
        }
    }
    float4 bv = *(const float4*)(b1 + lane * 4);
    float4 o4;
    o4.x = acc.x + bv.x; o4.x = o4.x > 0.f ? o4.x : expm1f(o4.x);
    o4.y = acc.y + bv.y; o4.y = o4.y > 0.f ? o4.y : expm1f(o4.y);
    o4.z = acc.z + bv.z; o4.z = o4.z > 0.f ? o4.z : expm1f(o4.z);
    o4.w = acc.w + bv.w; o4.w = o4.w > 0.f ? o4.w : expm1f(o4.w);
    ushort4 u;
    u.x = f2bf(o4.x); u.y = f2bf(o4.y); u.z = f2bf(o4.z); u.w = f2bf(o4.w);
    *(ushort4*)(out16 + (size_t)n * 256 + lane * 4) = u;
}

// Layer 2: one wave per node, 1 head, C=128; LDS cache; half-wave pairs in pass 3.
__global__ __launch_bounds__(256) void agg_l2(const int* __restrict__ rowptr,
                                              const int* __restrict__ col,
                                              const unsigned short* __restrict__ h16,
                                              const float* __restrict__ es,
                                              const float* __restrict__ ed,
                                              const float* __restrict__ b2,
                                              float* __restrict__ out, int N) {
    __shared__ float pl[4][DEG_CAP];
    __shared__ int ic[4][DEG_CAP];
    int wave = threadIdx.x >> 6, lane = threadIdx.x & 63;
    int n = blockIdx.x * 4 + wave;
    if (n >= N) return;
    int beg = rowptr[n], end = rowptr[n + 1], deg = end - beg;
    float edv = ed[n];
    float* myp = pl[wave];
    int* myc = ic[wave];
    float m = -INFINITY, z = 0.f, zinv;
    int half = lane >> 5, l32 = lane & 31;
    float4 acc = make_float4(0.f, 0.f, 0.f, 0.f);
    if (deg <= DEG_CAP) {
        for (int i = lane; i < deg; i += 64) {
            int s = col[beg + i];
            myc[i] = s;
            float e = es[s] + edv;
            e = e > 0.f ? e : 0.2f * e;
            myp[i] = e;
            m = fmaxf(m, e);
        }
        #pragma unroll
        for (int o = 32; o; o >>= 1) m = fmaxf(m, __shfl_xor(m, o));
        for (int i = lane; i < deg; i += 64) {
            float p = __expf(myp[i] - m);
            myp[i] = p;
            z += p;
        }
        #pragma unroll
        for (int o = 32; o; o >>= 1) z += __shfl_xor(z, o);
        zinv = 1.0f / z;
        __threadfence_block();
        for (int i = 0; i < deg; i += 2) {
            int ii = i + half;
            if (ii < deg) {
                float alpha = myp[ii] * zinv;
                ushort4 u = *(const ushort4*)(h16 + (size_t)myc[ii] * 128 + l32 * 4);
                acc.x = fmaf(alpha, bf2f(u.x), acc.x);
                acc.y = fmaf(alpha, bf2f(u.y), acc.y);
                acc.z = fmaf(alpha, bf2f(u.z), acc.z);
                acc.w = fmaf(alpha, bf2f(u.w), acc.w);
            }
        }
    } else {
        for (int e = beg + lane; e < end; e += 64) {
            float ev = es[col[e]] + edv;
            ev = ev > 0.f ? ev : 0.2f * ev;
            m = fmaxf(m, ev);
        }
        #pragma unroll
        for (int o = 32; o; o >>= 1) m = fmaxf(m, __shfl_xor(m, o));
        for (int e = beg + lane; e < end; e += 64) {
            float ev = es[col[e]] + edv;
            ev = ev > 0.f ? ev : 0.2f * ev;
            z += __expf(ev - m);
        }
        #pragma unroll
        for (int o = 32; o; o >>= 1) z += __shfl_xor(z, o);
        zinv = 1.0f / z;
        for (int e = beg; e < end; e += 2) {
            int ee = e + half;
            if (ee < end) {
                int s = col[ee];
                float ev = es[s] + edv;
                ev = ev > 0.f ? ev : 0.2f * ev;
                float alpha = __expf(ev - m) * zinv;
                ushort4 u = *(const ushort4*)(h16 + (size_t)s * 128 + l32 * 4);
                acc.x = fmaf(alpha, bf2f(u.x), acc.x);
                acc.y = fmaf(alpha, bf2f(u.y), acc.y);
                acc.z = fmaf(alpha, bf2f(u.z), acc.z);
                acc.w = fmaf(alpha, bf2f(u.w), acc.w);
            }
        }
    }
    acc.x += __shfl_xor(acc.x, 32);
    acc.y += __shfl_xor(acc.y, 32);
    acc.z += __shfl_xor(acc.z, 32);
    acc.w += __shfl_xor(acc.w, 32);
    if (half == 0) {
        float4 bv = *(const float4*)(b2 + l32 * 4);
        *(float4*)(out + (size_t)n * 128 + l32 * 4) =
            make_float4(acc.x + bv.x, acc.y + bv.y, acc.z + bv.z, acc.w + bv.w);
    }
}

// ===================== launch =====================
extern "C" void kernel_launch(void* const* d_in, const int* in_sizes, int n_in,
                              void* d_out, int out_size, void* d_ws, size_t ws_size,
                              hipStream_t stream) {
    const float* x   = (const float*)d_in[0];
    const int*   ei  = (const int*)d_in[1];
    const float* W1  = (const float*)d_in[2];
    const float* as1 = (const float*)d_in[3];
    const float* ad1 = (const float*)d_in[4];
    const float* b1  = (const float*)d_in[5];
    const float* W2  = (const float*)d_in[6];
    const float* as2 = (const float*)d_in[7];
    const float* ad2 = (const float*)d_in[8];
    const float* b2  = (const float*)d_in[9];
    float* out = (float*)d_out;

    const int N = in_sizes[0] / 128;   // 50000
    const int E = in_sizes[1] / 2;     // 800000
    const int Etot = E + N;
    const int* src = ei;
    const int* dst = ei + E;
    const int NB = (N + 255) / 256;

    // ---- workspace layout (16B-aligned chunks) ----
    char* p = (char*)d_ws;
    unsigned short* X16 = (unsigned short*)p; p += (size_t)N * 128 * 2;
    unsigned short* H16 = (unsigned short*)p; p += (size_t)N * 256 * 2;
    unsigned short* B16 = (unsigned short*)p; p += (size_t)N * 256 * 2;
    unsigned short* Wt1 = (unsigned short*)p; p += (size_t)256 * 128 * 2;
    unsigned short* Wt2 = (unsigned short*)p; p += (size_t)128 * 256 * 2;
    float* Q1  = (float*)p;               p += 128 * 8 * 4;
    float* Q2  = (float*)p;               p += 256 * 2 * 4;
    float* es1 = (float*)p;               p += (size_t)N * 4 * 4;
    float* ed1 = (float*)p;               p += (size_t)N * 4 * 4;
    float* es2 = (float*)p;               p += (size_t)N * 4;
    float* ed2 = (float*)p;               p += (size_t)N * 4;
    int* deg = (int*)p;                   p += (size_t)N * 4;
    int* partial = (int*)p;               p += (size_t)N * 4;
    int* cursor = (int*)p;                p += (size_t)N * 4;
    int* col = (int*)p;                   p += (size_t)Etot * 4;
    int* rowptr = (int*)p;                p += (size_t)(N + 1) * 4;
    int* bsum = (int*)p;                  p += 256 * 4;
    int* boff = (int*)p;                  p += 256 * 4;

    // ---- prep (conv + hist + Wt + Q, one launch) ----
    const int nx4 = N * 128 / 4;
    const int nb_convx = (nx4 + 255) / 256;
    const int nb_hist = (Etot + 255) / 256;
    const int nb_prep = nb_convx + nb_hist + 128 + 128 + 32 + 64;
    hipMemsetAsync(deg, 0, (size_t)N * sizeof(int), stream);
    prep<<<nb_prep, 256, 0, stream>>>(x, X16, nx4, dst, E, Etot, deg,
                                      W1, Wt1, W2, Wt2, as1, ad1, Q1,
                                      as2, ad2, Q2, nb_convx, nb_hist);

    // ---- CSR scan + scatter ----
    scan_local<<<NB, 256, 0, stream>>>(deg, partial, bsum, N);
    scan_sums<<<1, 256, 0, stream>>>(bsum, boff, NB);
    scan_add<<<NB, 256, 0, stream>>>(partial, boff, deg, rowptr, cursor, N);
    scatter_csr<<<(Etot + 255) / 256, 256, 0, stream>>>(src, dst, E, Etot, cursor, col);

    // ---- layer 1: GEMM+attn fused, then agg ----
    const int tiles = (N + 15) / 16;
    const int AB = (N + 3) / 4;
    const int GB1 = (tiles * 4 + 3) / 4;
    gemm_attn<128, 256, 4><<<GB1 + AB, 256, 0, stream>>>(X16, Wt1, Q1, H16,
                                                         es1, ed1, N, GB1);
    agg_l1<<<(N + 3) / 4, 256, 0, stream>>>(rowptr, col, H16, es1, ed1, b1, B16, N);

    // ---- layer 2 ----
    const int GB2 = (tiles * 2 + 3) / 4;
    gemm_attn<256, 128, 1><<<GB2 + AB, 256, 0, stream>>>(B16, Wt2, Q2, H16,
                                                         es2, ed2, N, GB2);
    agg_l2<<<(N + 3) / 4, 256, 0, stream>>>(rowptr, col, H16, es2, ed2, b2, out, N);
}